// Round 1
// baseline (1634.077 us; speedup 1.0000x reference)
//
#include <hip/hip_runtime.h>
#include <math.h>

#define C_   256
#define G_   4
#define K_   3
#define P_   9
#define GC_  64
#define H_   96
#define W_   96
#define N_   2
#define HW_  (H_*W_)          // 9216
#define CHW_ (C_*H_*W_)       // 2359296
#define OMC  108              // G*P*3
#define TILE 8                // pixels along w per block
#define NBW  (W_/TILE)        // 12 blocks per row

// ---------------- K1: depthwise conv + global sum/sumsq reduction ----------------
__global__ __launch_bounds__(256) void conv_stats_kernel(
    const float* __restrict__ x, const float* __restrict__ dw_w,
    const float* __restrict__ dw_b, float* __restrict__ sums)
{
    const int n = blockIdx.y;
    const int idx = blockIdx.x * 256 + threadIdx.x;      // [0, CHW)
    const int c = idx / HW_;
    const int rem = idx % HW_;
    const int h = rem / W_;
    const int w = rem % W_;
    const float* xb = x + ((size_t)n * C_ + c) * HW_;

    float wgt[9];
#pragma unroll
    for (int i = 0; i < 9; ++i) wgt[i] = dw_w[c * 9 + i];   // wave-uniform (same c per block)
    float v = dw_b[c];
#pragma unroll
    for (int r = 0; r < 3; ++r) {
        int y = h - 1 + r;
        if (y < 0 || y >= H_) continue;
#pragma unroll
        for (int s = 0; s < 3; ++s) {
            int xx = w - 1 + s;
            if (xx < 0 || xx >= W_) continue;
            v += wgt[r * 3 + s] * xb[y * W_ + xx];
        }
    }
    float s1 = v, s2 = v * v;
#pragma unroll
    for (int off = 32; off; off >>= 1) {
        s1 += __shfl_down(s1, off, 64);
        s2 += __shfl_down(s2, off, 64);
    }
    __shared__ float red[8];
    const int lane = threadIdx.x & 63, wv = threadIdx.x >> 6;
    if (lane == 0) { red[wv] = s1; red[4 + wv] = s2; }
    __syncthreads();
    if (threadIdx.x == 0) {
        float a = red[0] + red[1] + red[2] + red[3];
        float b = red[4] + red[5] + red[6] + red[7];
        atomicAdd(&sums[n * 2 + 0], a);
        atomicAdd(&sums[n * 2 + 1], b);
    }
}

// ---------------- K2: finalize mean / rstd ----------------
__global__ void stats_kernel(const float* __restrict__ sums, float* __restrict__ stats)
{
    int n = threadIdx.x;
    if (n < N_) {
        float m = sums[n * 2 + 0] * (1.0f / (float)CHW_);
        float v = sums[n * 2 + 1] * (1.0f / (float)CHW_) - m * m;
        stats[n * 2 + 0] = m;
        stats[n * 2 + 1] = rsqrtf(v + 1e-5f);
    }
}

// ---------------- K3: conv+norm+gelu -> om matmul -> softmax -> DCN sampling ----------------
__device__ __forceinline__ float fetch_x(const float* __restrict__ xc, int y, int xx)
{
    // (y,xx) are UNPADDED coords; pad border & validity both collapse to 0
    return (y >= 0 && y < H_ && xx >= 0 && xx < W_) ? xc[y * W_ + xx] : 0.0f;
}

__global__ __launch_bounds__(256) void main_kernel(
    const float* __restrict__ x, const float* __restrict__ unc,
    const float* __restrict__ dw_w, const float* __restrict__ dw_b,
    const float* __restrict__ stats,
    const float* __restrict__ gn_w, const float* __restrict__ gn_b,
    const float* __restrict__ om_w, const float* __restrict__ om_b,
    float* __restrict__ out)
{
    __shared__ float xs[256 * 30];       // x tile: [c][3 rows][10 cols]  (30.7 KB)
    __shared__ float feat[TILE * 257];   // normalized features, pix-major, pad-stride 257
    __shared__ float oms[TILE * 112];    // om outputs per pixel (108 used, pad to 112)

    const int tid = threadIdx.x;
    const int b = blockIdx.x;
    const int n = b / (H_ * NBW);
    const int rem = b % (H_ * NBW);
    const int h = rem / NBW;
    const int w0 = (rem % NBW) * TILE;

    // ---- Phase A: stage x[c, h-1..h+1, w0-1..w0+8] for all 256 channels ----
    const float* xb = x + (size_t)n * C_ * HW_;
    for (int e = tid; e < 256 * 30; e += 256) {
        int c = e / 30, q = e % 30, r = q / 10, i = q % 10;
        int gy = h - 1 + r, gx = w0 - 1 + i;
        float val = 0.0f;
        if (gy >= 0 && gy < H_ && gx >= 0 && gx < W_)
            val = xb[c * HW_ + gy * W_ + gx];
        xs[e] = val;
    }
    __syncthreads();

    // ---- Phase B: depthwise conv + groupnorm + exact GELU (thread = channel) ----
    {
        const int c = tid;
        float wgt[9];
#pragma unroll
        for (int i = 0; i < 9; ++i) wgt[i] = dw_w[c * 9 + i];
        const float bias = dw_b[c];
        const float mean = stats[n * 2 + 0];
        const float rstd = stats[n * 2 + 1];
        const float gw = gn_w[c], gb = gn_b[c];
        const float* xr = &xs[c * 30];
#pragma unroll
        for (int j = 0; j < TILE; ++j) {
            float v = bias;
#pragma unroll
            for (int r = 0; r < 3; ++r)
#pragma unroll
                for (int s = 0; s < 3; ++s)
                    v += wgt[r * 3 + s] * xr[r * 10 + j + s];
            float f = (v - mean) * rstd * gw + gb;
            f = 0.5f * f * (1.0f + erff(f * 0.70710678118654752f));
            feat[j * 257 + c] = f;
        }
    }
    __syncthreads();

    // ---- Phase C: om = feat @ om_w.T + om_b  (8 pixels x 108 outputs) ----
    for (int oid = tid; oid < TILE * OMC; oid += 256) {
        int pix = oid / OMC, j = oid % OMC;
        const float4* w4 = (const float4*)(om_w + j * 256);
        const float* fr = &feat[pix * 257];
        float acc = om_b[j];
#pragma unroll 4
        for (int cq = 0; cq < 64; ++cq) {
            float4 wv = w4[cq];
            acc += fr[cq * 4 + 0] * wv.x + fr[cq * 4 + 1] * wv.y
                 + fr[cq * 4 + 2] * wv.z + fr[cq * 4 + 3] * wv.w;
        }
        oms[pix * 112 + j] = acc;
    }
    __syncthreads();

    // ---- Phase D: softmax over P per (pixel, group), scaled by uncertainty ----
    if (tid < TILE * G_) {
        int pix = tid >> 2, g = tid & 3;
        float* m = &oms[pix * 112 + G_ * P_ * 2 + g * P_];
        float mx = m[0];
#pragma unroll
        for (int p = 1; p < P_; ++p) mx = fmaxf(mx, m[p]);
        float e[P_], s = 0.0f;
#pragma unroll
        for (int p = 0; p < P_; ++p) { e[p] = expf(m[p] - mx); s += e[p]; }
        float u = unc[(n * H_ + h) * W_ + w0 + pix];
        float inv = u / s;
#pragma unroll
        for (int p = 0; p < P_; ++p) m[p] = e[p] * inv;
    }
    __syncthreads();

    // ---- Phase E: DCNv3 bilinear sampling; thread = (group, group-channel) ----
    {
        const int g = tid >> 6;          // wave-uniform (one group per wave)
        const int gc = tid & 63;
        const int c = g * GC_ + gc;
        const float* xc = x + ((size_t)n * C_ + c) * HW_;
        float acc8[TILE];
#pragma unroll
        for (int pix = 0; pix < TILE; ++pix) {
            const float* po = &oms[pix * 112];
            const int w = w0 + pix;
            float acc = 0.0f;
#pragma unroll
            for (int p = 0; p < P_; ++p) {
                float ox = po[(g * P_ + p) * 2 + 0];
                float oy = po[(g * P_ + p) * 2 + 1];
                float mk = po[G_ * P_ * 2 + g * P_ + p];
                // padded coords: sx = (w+1) + px[p] + ox ; sy = (h+1) + py[p] + oy
                float sx = (float)(w + 1 + (p / 3) - 1) + ox;
                float sy = (float)(h + 1 + (p % 3) - 1) + oy;
                float x0f = floorf(sx), y0f = floorf(sy);
                float wx = sx - x0f, wy = sy - y0f;
                int x0 = (int)x0f, y0 = (int)y0f;
                // padded tap (y,x) -> x[y-1, x-1]
                float v00 = fetch_x(xc, y0 - 1, x0 - 1);
                float v01 = fetch_x(xc, y0 - 1, x0);
                float v10 = fetch_x(xc, y0,     x0 - 1);
                float v11 = fetch_x(xc, y0,     x0);
                float top = v00 + wx * (v01 - v00);
                float bot = v10 + wx * (v11 - v10);
                acc += mk * (top + wy * (bot - top));
            }
            acc8[pix] = acc;
        }
        float* outp = out + ((size_t)n * C_ + c) * HW_ + h * W_ + w0;
        float4 o0 = make_float4(acc8[0], acc8[1], acc8[2], acc8[3]);
        float4 o1 = make_float4(acc8[4], acc8[5], acc8[6], acc8[7]);
        ((float4*)outp)[0] = o0;
        ((float4*)outp)[1] = o1;
    }
}

extern "C" void kernel_launch(void* const* d_in, const int* in_sizes, int n_in,
                              void* d_out, int out_size, void* d_ws, size_t ws_size,
                              hipStream_t stream)
{
    const float* x    = (const float*)d_in[0];
    const float* unc  = (const float*)d_in[1];
    const float* dw_w = (const float*)d_in[2];
    const float* dw_b = (const float*)d_in[3];
    const float* gn_w = (const float*)d_in[4];
    const float* gn_b = (const float*)d_in[5];
    const float* om_w = (const float*)d_in[6];
    const float* om_b = (const float*)d_in[7];
    float* out = (float*)d_out;

    float* sums  = (float*)d_ws;       // 4 floats: per-n sum, sumsq
    float* stats = sums + 4;           // 4 floats: per-n mean, rstd

    hipMemsetAsync(d_ws, 0, 16, stream);
    conv_stats_kernel<<<dim3(CHW_ / 256, N_), 256, 0, stream>>>(x, dw_w, dw_b, sums);
    stats_kernel<<<1, 64, 0, stream>>>(sums, stats);
    main_kernel<<<N_ * H_ * NBW, 256, 0, stream>>>(x, unc, dw_w, dw_b, stats,
                                                   gn_w, gn_b, om_w, om_b, out);
}

// Round 2
// 604.237 us; speedup vs baseline: 2.7044x; 2.7044x over previous
//
#include <hip/hip_runtime.h>
#include <math.h>

#define C_   256
#define G_   4
#define K_   3
#define P_   9
#define GC_  64
#define H_   96
#define W_   96
#define N_   2
#define HW_  (H_*W_)          // 9216
#define CHW_ (C_*H_*W_)       // 2359296
#define OMC  108              // G*P*3
#define TILE 8                // pixels along w per block
#define NBW  (W_/TILE)        // 12 blocks per row
#define XS_STRIDE 31          // 30 data + 1 pad (break mod-32 bank aliasing)

// ---------------- K1: depthwise conv + global sum/sumsq reduction (4 px/thread) ----------------
__global__ __launch_bounds__(256) void conv_stats_kernel(
    const float* __restrict__ x, const float* __restrict__ dw_w,
    const float* __restrict__ dw_b, float* __restrict__ sums)
{
    const int n = blockIdx.y;
    const int idx = blockIdx.x * 256 + threadIdx.x;      // [0, CHW/4)
    const int c = idx / (HW_ / 4);                       // 2304 per channel; 9 blocks/channel
    const int rem = idx % (HW_ / 4);
    const int h = rem / (W_ / 4);
    const int w0 = (rem % (W_ / 4)) * 4;
    const float* xb = x + ((size_t)n * C_ + c) * HW_;

    float wgt[9];
#pragma unroll
    for (int i = 0; i < 9; ++i) wgt[i] = dw_w[c * 9 + i];   // c uniform per block
    const float bias = dw_b[c];
    float acc[4] = {bias, bias, bias, bias};
#pragma unroll
    for (int r = 0; r < 3; ++r) {
        int y = h - 1 + r;
        if (y < 0 || y >= H_) continue;
        const float* row = xb + y * W_;
        float4 m = *(const float4*)(row + w0);
        float e0 = (w0 > 0) ? row[w0 - 1] : 0.0f;
        float e5 = (w0 + 4 < W_) ? row[w0 + 4] : 0.0f;
        float e[6] = {e0, m.x, m.y, m.z, m.w, e5};
#pragma unroll
        for (int j = 0; j < 4; ++j)
            acc[j] += wgt[r * 3 + 0] * e[j] + wgt[r * 3 + 1] * e[j + 1] + wgt[r * 3 + 2] * e[j + 2];
    }
    float s1 = 0.0f, s2 = 0.0f;
#pragma unroll
    for (int j = 0; j < 4; ++j) { s1 += acc[j]; s2 += acc[j] * acc[j]; }
#pragma unroll
    for (int off = 32; off; off >>= 1) {
        s1 += __shfl_down(s1, off, 64);
        s2 += __shfl_down(s2, off, 64);
    }
    __shared__ float red[8];
    const int lane = threadIdx.x & 63, wv = threadIdx.x >> 6;
    if (lane == 0) { red[wv] = s1; red[4 + wv] = s2; }
    __syncthreads();
    if (threadIdx.x == 0) {
        float a = red[0] + red[1] + red[2] + red[3];
        float b = red[4] + red[5] + red[6] + red[7];
        atomicAdd(&sums[n * 2 + 0], a);
        atomicAdd(&sums[n * 2 + 1], b);
    }
}

// ---------------- K2: finalize mean / rstd ----------------
__global__ void stats_kernel(const float* __restrict__ sums, float* __restrict__ stats)
{
    int n = threadIdx.x;
    if (n < N_) {
        float m = sums[n * 2 + 0] * (1.0f / (float)CHW_);
        float v = sums[n * 2 + 1] * (1.0f / (float)CHW_) - m * m;
        stats[n * 2 + 0] = m;
        stats[n * 2 + 1] = rsqrtf(v + 1e-5f);
    }
}

// ---------------- K3: conv+norm+gelu -> om matmul -> softmax -> DCN sampling ----------------
__global__ __launch_bounds__(256, 3) void main_kernel(
    const float* __restrict__ x, const float* __restrict__ unc,
    const float* __restrict__ dw_w, const float* __restrict__ dw_b,
    const float* __restrict__ stats,
    const float* __restrict__ gn_w, const float* __restrict__ gn_b,
    const float* __restrict__ om_w, const float* __restrict__ om_b,
    float* __restrict__ out)
{
    __shared__ float xs[256 * XS_STRIDE]; // x tile: [c][3 rows][10 cols], stride 31 (31.7 KB)
    __shared__ float feat[TILE * 257];    // normalized features, pix-major, pad-stride 257
    __shared__ float oms[TILE * 112];     // om outputs per pixel (108 used, pad to 112)

    const int tid = threadIdx.x;
    const int b = blockIdx.x;
    const int n = b / (H_ * NBW);
    const int rem = b % (H_ * NBW);
    const int h = rem / NBW;
    const int w0 = (rem % NBW) * TILE;

    // ---- Phase A: stage x[c, h-1..h+1, w0-1..w0+8] for all 256 channels ----
    const float* xb = x + (size_t)n * C_ * HW_;
    for (int e = tid; e < 256 * 30; e += 256) {
        int c = e / 30, q = e % 30, r = q / 10, i = q % 10;
        int gy = h - 1 + r, gx = w0 - 1 + i;
        float val = 0.0f;
        if (gy >= 0 && gy < H_ && gx >= 0 && gx < W_)
            val = xb[c * HW_ + gy * W_ + gx];
        xs[c * XS_STRIDE + q] = val;
    }
    __syncthreads();

    // ---- Phase B: depthwise conv + groupnorm + exact GELU (thread = channel) ----
    {
        const int c = tid;
        float wgt[9];
#pragma unroll
        for (int i = 0; i < 9; ++i) wgt[i] = dw_w[c * 9 + i];
        const float bias = dw_b[c];
        const float mean = stats[n * 2 + 0];
        const float rstd = stats[n * 2 + 1];
        const float gw = gn_w[c], gb = gn_b[c];
        const float* xr = &xs[c * XS_STRIDE];
#pragma unroll
        for (int j = 0; j < TILE; ++j) {
            float v = bias;
#pragma unroll
            for (int r = 0; r < 3; ++r)
#pragma unroll
                for (int s = 0; s < 3; ++s)
                    v += wgt[r * 3 + s] * xr[r * 10 + j + s];
            float f = (v - mean) * rstd * gw + gb;
            f = 0.5f * f * (1.0f + erff(f * 0.70710678118654752f));
            feat[j * 257 + c] = f;
        }
    }
    __syncthreads();

    // ---- Phase C: om = feat @ om_w.T + om_b  (8 pixels x 108 outputs) ----
    for (int oid = tid; oid < TILE * OMC; oid += 256) {
        int pix = oid / OMC, j = oid % OMC;
        const float4* w4 = (const float4*)(om_w + j * 256);
        const float* fr = &feat[pix * 257];
        float acc = om_b[j];
#pragma unroll 4
        for (int cq = 0; cq < 64; ++cq) {
            float4 wv = w4[cq];
            acc += fr[cq * 4 + 0] * wv.x + fr[cq * 4 + 1] * wv.y
                 + fr[cq * 4 + 2] * wv.z + fr[cq * 4 + 3] * wv.w;
        }
        oms[pix * 112 + j] = acc;
    }
    __syncthreads();

    // ---- Phase D: softmax over P per (pixel, group), scaled by uncertainty ----
    if (tid < TILE * G_) {
        int pix = tid >> 2, g = tid & 3;
        float* m = &oms[pix * 112 + G_ * P_ * 2 + g * P_];
        float mx = m[0];
#pragma unroll
        for (int p = 1; p < P_; ++p) mx = fmaxf(mx, m[p]);
        float e[P_], s = 0.0f;
#pragma unroll
        for (int p = 0; p < P_; ++p) { e[p] = expf(m[p] - mx); s += e[p]; }
        float u = unc[(n * H_ + h) * W_ + w0 + pix];
        float inv = u / s;
#pragma unroll
        for (int p = 0; p < P_; ++p) m[p] = e[p] * inv;
    }
    __syncthreads();

    // ---- Phase E: DCNv3 bilinear sampling ----
    // wave = group g; lane = csub*8 + pix; each lane: 1 pixel x 8 channels (stride 8)
    {
        const int g = tid >> 6;
        const int lane = tid & 63;
        const int csub = lane >> 3;          // 0..7
        const int pix = lane & 7;            // 0..7
        const int w = w0 + pix;
        const float* xg = x + ((size_t)n * C_ + g * GC_ + csub) * HW_;
        const float* po = &oms[pix * 112];
        float acc[8];
#pragma unroll
        for (int k = 0; k < 8; ++k) acc[k] = 0.0f;

#pragma unroll 1
        for (int p = 0; p < P_; ++p) {
            float ox = po[(g * P_ + p) * 2 + 0];
            float oy = po[(g * P_ + p) * 2 + 1];
            float mk = po[G_ * P_ * 2 + g * P_ + p];
            // unpadded sampling coords: sx = w + p/3 + ox ; sy = h + p%3 + oy ; taps at floor-1
            float sx = (float)(w + (p / 3)) + ox;
            float sy = (float)(h + (p % 3)) + oy;
            float x0f = floorf(sx), y0f = floorf(sy);
            float wx = sx - x0f, wy = sy - y0f;
            int x0 = (int)x0f - 1, y0 = (int)y0f - 1;   // top-left tap, unpadded
            float fy0 = (y0 >= 0 && y0 < H_) ? 1.0f : 0.0f;
            float fy1 = (y0 + 1 >= 0 && y0 + 1 < H_) ? 1.0f : 0.0f;
            float fx0 = (x0 >= 0 && x0 < W_) ? 1.0f : 0.0f;
            float fx1 = (x0 + 1 >= 0 && x0 + 1 < W_) ? 1.0f : 0.0f;
            int y0c = min(max(y0, 0), H_ - 1), y1c = min(max(y0 + 1, 0), H_ - 1);
            int x0c = min(max(x0, 0), W_ - 1), x1c = min(max(x0 + 1, 0), W_ - 1);
            int o00 = y0c * W_ + x0c, o01 = y0c * W_ + x1c;
            int o10 = y1c * W_ + x0c, o11 = y1c * W_ + x1c;
            float w00 = (1.0f - wy) * (1.0f - wx) * mk * fy0 * fx0;
            float w01 = (1.0f - wy) * wx * mk * fy0 * fx1;
            float w10 = wy * (1.0f - wx) * mk * fy1 * fx0;
            float w11 = wy * wx * mk * fy1 * fx1;
#pragma unroll
            for (int k = 0; k < 8; ++k) {
                const float* xc = xg + (size_t)(k * 8) * HW_;
                acc[k] += w00 * xc[o00] + w01 * xc[o01] + w10 * xc[o10] + w11 * xc[o11];
            }
        }
        float* outp = out + ((size_t)n * C_ + g * GC_ + csub) * HW_ + h * W_ + w;
#pragma unroll
        for (int k = 0; k < 8; ++k) outp[(size_t)(k * 8) * HW_] = acc[k];
    }
}

extern "C" void kernel_launch(void* const* d_in, const int* in_sizes, int n_in,
                              void* d_out, int out_size, void* d_ws, size_t ws_size,
                              hipStream_t stream)
{
    const float* x    = (const float*)d_in[0];
    const float* unc  = (const float*)d_in[1];
    const float* dw_w = (const float*)d_in[2];
    const float* dw_b = (const float*)d_in[3];
    const float* gn_w = (const float*)d_in[4];
    const float* gn_b = (const float*)d_in[5];
    const float* om_w = (const float*)d_in[6];
    const float* om_b = (const float*)d_in[7];
    float* out = (float*)d_out;

    float* sums  = (float*)d_ws;       // 4 floats: per-n sum, sumsq
    float* stats = sums + 4;           // 4 floats: per-n mean, rstd

    hipMemsetAsync(d_ws, 0, 16, stream);
    conv_stats_kernel<<<dim3(CHW_ / 4 / 256, N_), 256, 0, stream>>>(x, dw_w, dw_b, sums);
    stats_kernel<<<1, 64, 0, stream>>>(sums, stats);
    main_kernel<<<N_ * H_ * NBW, 256, 0, stream>>>(x, unc, dw_w, dw_b, stats,
                                                   gn_w, gn_b, om_w, om_b, out);
}

// Round 3
// 595.954 us; speedup vs baseline: 2.7420x; 1.0139x over previous
//
#include <hip/hip_runtime.h>
#include <hip/hip_bf16.h>
#include <math.h>

#define C_   256
#define G_   4
#define P_   9
#define GC_  64
#define H_   96
#define W_   96
#define N_   2
#define HW_  (H_*W_)          // 9216
#define CHW_ (C_*H_*W_)       // 2359296
#define OMC  108              // G*P*3
#define TILE 8                // pixels along w per block
#define NBW  (W_/TILE)        // 12
#define NBLK (N_*H_*NBW)      // 2304 tiles
#define XS_STRIDE 31          // break mod-32 bank aliasing
#define FEAT_STRIDE 260       // 16B-aligned rows, conflict-free b128 reads
#define OMS_STRIDE 114        // even (aligned float2), odd/16 banks spread

// ws layout (bytes):
//   [0)        partials: NBLK * 2 floats          (18432 B)
//   [18432)    stats: 4 floats (mean0,rstd0,mean1,rstd1)
//   [32768)    ctx bf16 NHWC: 18432 px * 256 ch   (9.44 MB)

// ---------------- K1: depthwise conv -> ctx(bf16, NHWC) + block partial sums ----------------
__global__ __launch_bounds__(256) void conv_ctx_kernel(
    const float* __restrict__ x, const float* __restrict__ dw_w,
    const float* __restrict__ dw_b, __hip_bfloat16* __restrict__ ctx,
    float* __restrict__ partials)
{
    __shared__ float xs[256 * XS_STRIDE];
    const int tid = threadIdx.x;
    const int b = blockIdx.x;
    const int n = b / (H_ * NBW);
    const int rem = b % (H_ * NBW);
    const int h = rem / NBW;
    const int w0 = (rem % NBW) * TILE;

    // stage x[c, h-1..h+1, w0-1..w0+8] for all 256 channels
    const float* xb = x + (size_t)n * C_ * HW_;
    for (int e = tid; e < 256 * 30; e += 256) {
        int c = e / 30, q = e % 30, r = q / 10, i = q % 10;
        int gy = h - 1 + r, gx = w0 - 1 + i;
        float val = 0.0f;
        if (gy >= 0 && gy < H_ && gx >= 0 && gx < W_)
            val = xb[c * HW_ + gy * W_ + gx];
        xs[c * XS_STRIDE + q] = val;
    }
    __syncthreads();

    const int c = tid;
    float wgt[9];
#pragma unroll
    for (int i = 0; i < 9; ++i) wgt[i] = dw_w[c * 9 + i];
    const float bias = dw_b[c];
    const float* xr = &xs[c * XS_STRIDE];
    __hip_bfloat16* cbase = ctx + (size_t)((n * H_ + h) * W_ + w0) * C_ + c;
    float s1 = 0.0f, s2 = 0.0f;
#pragma unroll
    for (int j = 0; j < TILE; ++j) {
        float v = bias;
#pragma unroll
        for (int r = 0; r < 3; ++r)
#pragma unroll
            for (int s = 0; s < 3; ++s)
                v += wgt[r * 3 + s] * xr[r * 10 + j + s];
        s1 += v; s2 += v * v;
        cbase[j * C_] = __float2bfloat16(v);
    }
#pragma unroll
    for (int off = 32; off; off >>= 1) {
        s1 += __shfl_down(s1, off, 64);
        s2 += __shfl_down(s2, off, 64);
    }
    __shared__ float red[8];
    const int lane = tid & 63, wv = tid >> 6;
    if (lane == 0) { red[wv] = s1; red[4 + wv] = s2; }
    __syncthreads();
    if (tid == 0) {
        partials[b * 2 + 0] = red[0] + red[1] + red[2] + red[3];
        partials[b * 2 + 1] = red[4] + red[5] + red[6] + red[7];
    }
}

// ---------------- K2: reduce partials -> mean/rstd per n ----------------
__global__ __launch_bounds__(256) void stats_kernel(
    const float* __restrict__ partials, float* __restrict__ stats)
{
    const int tid = threadIdx.x;
    float a0 = 0, b0 = 0, a1 = 0, b1 = 0;
    for (int i = tid; i < NBLK; i += 256) {
        float p1 = partials[i * 2 + 0], p2 = partials[i * 2 + 1];
        if (i < NBLK / 2) { a0 += p1; b0 += p2; }
        else              { a1 += p1; b1 += p2; }
    }
#pragma unroll
    for (int off = 32; off; off >>= 1) {
        a0 += __shfl_down(a0, off, 64); b0 += __shfl_down(b0, off, 64);
        a1 += __shfl_down(a1, off, 64); b1 += __shfl_down(b1, off, 64);
    }
    __shared__ float red[4][4];
    const int lane = tid & 63, wv = tid >> 6;
    if (lane == 0) { red[wv][0] = a0; red[wv][1] = b0; red[wv][2] = a1; red[wv][3] = b1; }
    __syncthreads();
    if (tid == 0) {
        float A0 = red[0][0] + red[1][0] + red[2][0] + red[3][0];
        float B0 = red[0][1] + red[1][1] + red[2][1] + red[3][1];
        float A1 = red[0][2] + red[1][2] + red[2][2] + red[3][2];
        float B1 = red[0][3] + red[1][3] + red[2][3] + red[3][3];
        float m0 = A0 * (1.0f / (float)CHW_);
        float v0 = B0 * (1.0f / (float)CHW_) - m0 * m0;
        float m1 = A1 * (1.0f / (float)CHW_);
        float v1 = B1 * (1.0f / (float)CHW_) - m1 * m1;
        stats[0] = m0; stats[1] = rsqrtf(v0 + 1e-5f);
        stats[2] = m1; stats[3] = rsqrtf(v1 + 1e-5f);
    }
}

// ---------------- K3: norm+gelu -> om matmul -> softmax -> DCN sampling ----------------
__global__ __launch_bounds__(256, 6) void main_kernel(
    const float* __restrict__ x, const float* __restrict__ unc,
    const __hip_bfloat16* __restrict__ ctx, const float* __restrict__ stats,
    const float* __restrict__ gn_w, const float* __restrict__ gn_b,
    const float* __restrict__ om_w, const float* __restrict__ om_b,
    float* __restrict__ out)
{
    __shared__ float feat[TILE * FEAT_STRIDE];  // 8.3 KB
    __shared__ float oms[TILE * OMS_STRIDE];    // 3.6 KB

    const int tid = threadIdx.x;
    const int b = blockIdx.x;
    const int n = b / (H_ * NBW);
    const int rem = b % (H_ * NBW);
    const int h = rem / NBW;
    const int w0 = (rem % NBW) * TILE;

    // ---- Phase B: load ctx (coalesced) + groupnorm + exact GELU (thread = channel) ----
    {
        const int c = tid;
        const float mean = stats[n * 2 + 0];
        const float rstd = stats[n * 2 + 1];
        const float gw = gn_w[c], gb = gn_b[c];
        const __hip_bfloat16* cbase = ctx + (size_t)((n * H_ + h) * W_ + w0) * C_ + c;
#pragma unroll
        for (int j = 0; j < TILE; ++j) {
            float v = __bfloat162float(cbase[j * C_]);
            float f = (v - mean) * rstd * gw + gb;
            f = 0.5f * f * (1.0f + erff(f * 0.70710678118654752f));
            feat[j * FEAT_STRIDE + c] = f;
        }
    }
    __syncthreads();

    // ---- Phase C: om = feat @ om_w.T + om_b, wave-cooperative coalesced ----
    // wave wv handles j = wv + 4*slot; lane = ig*16+kk; lane kk owns K-cols kk*4+{0,64,128,192}
    {
        const int wv = tid >> 6;
        const int lane = tid & 63;
        const int ig = lane >> 4;       // j subgroup 0..3
        const int kk = lane & 15;       // k chunk
#pragma unroll 1
        for (int bb = 0; bb < 7; ++bb) {
            int slot = bb * 4 + ig;                 // 0..27
            int j = wv + 4 * min(slot, 26);         // clamped redundant load for slot==27
            const float* wrow = om_w + j * 256 + kk * 4;
            float4 w0v = *(const float4*)(wrow);
            float4 w1v = *(const float4*)(wrow + 64);
            float4 w2v = *(const float4*)(wrow + 128);
            float4 w3v = *(const float4*)(wrow + 192);
            float d[TILE];
#pragma unroll
            for (int pix = 0; pix < TILE; ++pix) {
                const float* fr = feat + pix * FEAT_STRIDE + kk * 4;
                float4 f0 = *(const float4*)(fr);
                float4 f1 = *(const float4*)(fr + 64);
                float4 f2 = *(const float4*)(fr + 128);
                float4 f3 = *(const float4*)(fr + 192);
                d[pix] = f0.x * w0v.x + f0.y * w0v.y + f0.z * w0v.z + f0.w * w0v.w
                       + f1.x * w1v.x + f1.y * w1v.y + f1.z * w1v.z + f1.w * w1v.w
                       + f2.x * w2v.x + f2.y * w2v.y + f2.z * w2v.z + f2.w * w2v.w
                       + f3.x * w3v.x + f3.y * w3v.y + f3.z * w3v.z + f3.w * w3v.w;
            }
#pragma unroll
            for (int m = 1; m <= 8; m <<= 1)
#pragma unroll
                for (int pix = 0; pix < TILE; ++pix)
                    d[pix] += __shfl_xor(d[pix], m, 64);
            if (slot < 27 && kk < TILE)
                oms[kk * OMS_STRIDE + j] = d[kk] + om_b[j];
        }
    }
    __syncthreads();

    // ---- Phase D: softmax over P per (pixel, group), scaled by uncertainty ----
    if (tid < TILE * G_) {
        int pix = tid >> 2, g = tid & 3;
        float* m = &oms[pix * OMS_STRIDE + G_ * P_ * 2 + g * P_];
        float mx = m[0];
#pragma unroll
        for (int p = 1; p < P_; ++p) mx = fmaxf(mx, m[p]);
        float e[P_], s = 0.0f;
#pragma unroll
        for (int p = 0; p < P_; ++p) { e[p] = expf(m[p] - mx); s += e[p]; }
        float u = unc[(n * H_ + h) * W_ + w0 + pix];
        float inv = u / s;
#pragma unroll
        for (int p = 0; p < P_; ++p) m[p] = e[p] * inv;
    }
    __syncthreads();

    // ---- Phase E: DCNv3 bilinear sampling; lane = csub*8 + pix; 8 ch x 1 pix per lane ----
    {
        const int g = tid >> 6;
        const int lane = tid & 63;
        const int csub = lane >> 3;          // 0..7
        const int pix = lane & 7;            // 0..7
        const int w = w0 + pix;
        const float* xg = x + ((size_t)n * C_ + g * GC_ + csub) * HW_;
        const float* po = &oms[pix * OMS_STRIDE];
        const float2* po2 = (const float2*)po;
        float acc[8];
#pragma unroll
        for (int k = 0; k < 8; ++k) acc[k] = 0.0f;

#pragma unroll 1
        for (int p = 0; p < P_; ++p) {
            float2 oxy = po2[g * P_ + p];
            float mk = po[G_ * P_ * 2 + g * P_ + p];
            float sx = (float)(w + (p / 3)) + oxy.x;
            float sy = (float)(h + (p % 3)) + oxy.y;
            float x0f = floorf(sx), y0f = floorf(sy);
            float wx = sx - x0f, wy = sy - y0f;
            int x0 = (int)x0f - 1, y0 = (int)y0f - 1;   // top-left tap, unpadded
            float fy0 = (y0 >= 0 && y0 < H_) ? 1.0f : 0.0f;
            float fy1 = (y0 + 1 >= 0 && y0 + 1 < H_) ? 1.0f : 0.0f;
            float fx0 = (x0 >= 0 && x0 < W_) ? 1.0f : 0.0f;
            float fx1 = (x0 + 1 >= 0 && x0 + 1 < W_) ? 1.0f : 0.0f;
            int y0c = min(max(y0, 0), H_ - 1), y1c = min(max(y0 + 1, 0), H_ - 1);
            int x0c = min(max(x0, 0), W_ - 1), x1c = min(max(x0 + 1, 0), W_ - 1);
            int o00 = y0c * W_ + x0c, o01 = y0c * W_ + x1c;
            int o10 = y1c * W_ + x0c, o11 = y1c * W_ + x1c;
            float w00 = (1.0f - wy) * (1.0f - wx) * mk * fy0 * fx0;
            float w01 = (1.0f - wy) * wx * mk * fy0 * fx1;
            float w10 = wy * (1.0f - wx) * mk * fy1 * fx0;
            float w11 = wy * wx * mk * fy1 * fx1;
#pragma unroll
            for (int k = 0; k < 8; ++k) {
                const float* xc = xg + (size_t)(k * 8) * HW_;
                acc[k] += w00 * xc[o00] + w01 * xc[o01] + w10 * xc[o10] + w11 * xc[o11];
            }
        }
        float* outp = out + ((size_t)n * C_ + g * GC_ + csub) * HW_ + h * W_ + w;
#pragma unroll
        for (int k = 0; k < 8; ++k) outp[(size_t)(k * 8) * HW_] = acc[k];
    }
}

extern "C" void kernel_launch(void* const* d_in, const int* in_sizes, int n_in,
                              void* d_out, int out_size, void* d_ws, size_t ws_size,
                              hipStream_t stream)
{
    const float* x    = (const float*)d_in[0];
    const float* unc  = (const float*)d_in[1];
    const float* dw_w = (const float*)d_in[2];
    const float* dw_b = (const float*)d_in[3];
    const float* gn_w = (const float*)d_in[4];
    const float* gn_b = (const float*)d_in[5];
    const float* om_w = (const float*)d_in[6];
    const float* om_b = (const float*)d_in[7];
    float* out = (float*)d_out;

    float* partials = (float*)d_ws;                            // NBLK*2 floats
    float* stats    = (float*)((char*)d_ws + NBLK * 2 * 4);    // 4 floats
    __hip_bfloat16* ctx = (__hip_bfloat16*)((char*)d_ws + 32768);

    conv_ctx_kernel<<<NBLK, 256, 0, stream>>>(x, dw_w, dw_b, ctx, partials);
    stats_kernel<<<1, 256, 0, stream>>>(partials, stats);
    main_kernel<<<NBLK, 256, 0, stream>>>(x, unc, ctx, stats,
                                          gn_w, gn_b, om_w, om_b, out);
}

// Round 4
// 197.296 us; speedup vs baseline: 8.2824x; 3.0206x over previous
//
#include <hip/hip_runtime.h>
#include <hip/hip_bf16.h>
#include <math.h>

#define C_   256
#define G_   4
#define P_   9
#define GC_  64
#define H_   96
#define W_   96
#define N_   2
#define HW_  (H_*W_)          // 9216
#define CHW_ (C_*H_*W_)       // 2359296
#define OMC  108              // G*P*3
#define TILE 16               // pixels along w per block
#define NBW  (W_/TILE)        // 6
#define NBLK (N_*H_*NBW)      // 1152
#define FEAT_STRIDE 260       // dwords; 16B-aligned rows
#define OMS_STRIDE 114
#define TBUF_STRIDE 17        // odd -> conflict-free column writes

// ws layout (bytes):
//   [0)        partials: NBLK*2 floats (9216 B), indexed by TILE id
//   [12288)    stats: 4 floats
//   [32768)    xn  bf16 NHWC: N*H*W*C   (9.44 MB)
//   [32768+9437184) ctx bf16 NHWC       (9.44 MB)

// ---------------- K0: x NCHW f32 -> xn NHWC bf16 (tiled transpose) ----------------
__global__ __launch_bounds__(256) void transpose_kernel(
    const float* __restrict__ x, __hip_bfloat16* __restrict__ xn)
{
    __shared__ float t[32 * 33];
    const int b = blockIdx.x;                 // 4608 = 8 xcd * 576
    const int xcd = b & 7, idx = b >> 3;
    const int job = xcd * 576 + idx;          // xcd gets contiguous (n,h) span
    const int nh = job / 24;                  // 24 (c,w)-tiles per (n,h)
    const int r = job % 24;
    const int c0 = (r / 3) * 32;
    const int w0 = (r % 3) * 32;
    const int n = nh / H_, h = nh % H_;
    const int tx = threadIdx.x & 31, ty = threadIdx.x >> 5;   // ty 0..7
#pragma unroll
    for (int rr = 0; rr < 4; ++rr) {
        int cl = ty + rr * 8;
        t[cl * 33 + tx] = x[(((size_t)n * C_ + c0 + cl) * H_ + h) * W_ + w0 + tx];
    }
    __syncthreads();
#pragma unroll
    for (int rr = 0; rr < 4; ++rr) {
        int wl = ty + rr * 8;
        xn[(((size_t)n * H_ + h) * W_ + w0 + wl) * C_ + c0 + tx] =
            __float2bfloat16(t[tx * 33 + wl]);
    }
}

// ---------------- K1: depthwise conv (NHWC) -> ctx bf16 + per-tile partial sums ----------------
__global__ __launch_bounds__(256) void conv_ctx_kernel(
    const __hip_bfloat16* __restrict__ xn, const float* __restrict__ dw_w,
    const float* __restrict__ dw_b, __hip_bfloat16* __restrict__ ctx,
    float* __restrict__ partials)
{
    const int b = blockIdx.x;
    const int xcd = b & 7, idx = b >> 3;
    const int tile = xcd * (NBLK / 8) + idx;
    const int n = tile / (H_ * NBW);
    const int r = tile % (H_ * NBW);
    const int h = r / NBW;
    const int w0 = (r % NBW) * TILE;
    const int c = threadIdx.x;

    float xv[3][TILE + 2];
    const __hip_bfloat16* xb = xn + (size_t)n * HW_ * C_ + c;
#pragma unroll
    for (int r3 = 0; r3 < 3; ++r3) {
        int gy = h - 1 + r3;
        bool vy = (gy >= 0 && gy < H_);
#pragma unroll
        for (int i = 0; i < TILE + 2; ++i) {
            int gx = w0 - 1 + i;
            xv[r3][i] = (vy && gx >= 0 && gx < W_)
                ? __bfloat162float(xb[((size_t)gy * W_ + gx) * C_]) : 0.0f;
        }
    }
    float wgt[9];
#pragma unroll
    for (int i = 0; i < 9; ++i) wgt[i] = dw_w[c * 9 + i];
    const float bias = dw_b[c];
    __hip_bfloat16* cb = ctx + ((size_t)(n * H_ + h) * W_ + w0) * C_ + c;
    float s1 = 0.0f, s2 = 0.0f;
#pragma unroll
    for (int j = 0; j < TILE; ++j) {
        float v = bias;
#pragma unroll
        for (int r3 = 0; r3 < 3; ++r3)
#pragma unroll
            for (int s = 0; s < 3; ++s)
                v += wgt[r3 * 3 + s] * xv[r3][j + s];
        s1 += v; s2 += v * v;
        cb[j * C_] = __float2bfloat16(v);
    }
#pragma unroll
    for (int off = 32; off; off >>= 1) {
        s1 += __shfl_down(s1, off, 64);
        s2 += __shfl_down(s2, off, 64);
    }
    __shared__ float red[8];
    const int lane = threadIdx.x & 63, wv = threadIdx.x >> 6;
    if (lane == 0) { red[wv] = s1; red[4 + wv] = s2; }
    __syncthreads();
    if (threadIdx.x == 0) {
        partials[tile * 2 + 0] = red[0] + red[1] + red[2] + red[3];
        partials[tile * 2 + 1] = red[4] + red[5] + red[6] + red[7];
    }
}

// ---------------- K2: reduce partials -> mean/rstd per n ----------------
__global__ __launch_bounds__(256) void stats_kernel(
    const float* __restrict__ partials, float* __restrict__ stats)
{
    const int tid = threadIdx.x;
    float a0 = 0, b0 = 0, a1 = 0, b1 = 0;
    for (int i = tid; i < NBLK; i += 256) {
        float p1 = partials[i * 2 + 0], p2 = partials[i * 2 + 1];
        if (i < NBLK / 2) { a0 += p1; b0 += p2; }
        else              { a1 += p1; b1 += p2; }
    }
#pragma unroll
    for (int off = 32; off; off >>= 1) {
        a0 += __shfl_down(a0, off, 64); b0 += __shfl_down(b0, off, 64);
        a1 += __shfl_down(a1, off, 64); b1 += __shfl_down(b1, off, 64);
    }
    __shared__ float red[4][4];
    const int lane = tid & 63, wv = tid >> 6;
    if (lane == 0) { red[wv][0] = a0; red[wv][1] = b0; red[wv][2] = a1; red[wv][3] = b1; }
    __syncthreads();
    if (tid == 0) {
        float A0 = red[0][0] + red[1][0] + red[2][0] + red[3][0];
        float B0 = red[0][1] + red[1][1] + red[2][1] + red[3][1];
        float A1 = red[0][2] + red[1][2] + red[2][2] + red[3][2];
        float B1 = red[0][3] + red[1][3] + red[2][3] + red[3][3];
        float m0 = A0 * (1.0f / (float)CHW_);
        float v0 = B0 * (1.0f / (float)CHW_) - m0 * m0;
        float m1 = A1 * (1.0f / (float)CHW_);
        float v1 = B1 * (1.0f / (float)CHW_) - m1 * m1;
        stats[0] = m0; stats[1] = rsqrtf(v0 + 1e-5f);
        stats[2] = m1; stats[3] = rsqrtf(v1 + 1e-5f);
    }
}

// ---------------- K3: norm+gelu -> om matmul -> softmax -> table -> sampling ----------------
__global__ __launch_bounds__(256, 4) void main_kernel(
    const __hip_bfloat16* __restrict__ xn, const float* __restrict__ unc,
    const __hip_bfloat16* __restrict__ ctx, const float* __restrict__ stats,
    const float* __restrict__ gn_w, const float* __restrict__ gn_b,
    const float* __restrict__ om_w, const float* __restrict__ om_b,
    float* __restrict__ out)
{
    // Region A [0,18432): feat (16x260 f32, 16640 B) then tap-table (576x32 B)
    // Region B [18432, +17408): oms (16x114 f32, 7296 B) then tbuf (256x17 f32)
    __shared__ char smem[18432 + 17408];
    float* feat = (float*)smem;
    char* table = smem;
    float* oms  = (float*)(smem + 18432);
    float* tbuf = (float*)(smem + 18432);

    const int tid = threadIdx.x;
    const int b = blockIdx.x;
    const int xcd = b & 7, idx = b >> 3;
    const int tile = xcd * (NBLK / 8) + idx;   // xcd owns 24 contiguous rows
    const int n = tile / (H_ * NBW);
    const int rem = tile % (H_ * NBW);
    const int h = rem / NBW;
    const int w0 = (rem % NBW) * TILE;

    // ---- Phase B: ctx load (coalesced bf16) + groupnorm + exact GELU ----
    {
        const int c = tid;
        const float mean = stats[n * 2 + 0];
        const float rstd = stats[n * 2 + 1];
        const float gw = gn_w[c], gb = gn_b[c];
        const __hip_bfloat16* cb = ctx + ((size_t)(n * H_ + h) * W_ + w0) * C_ + c;
#pragma unroll
        for (int j = 0; j < TILE; ++j) {
            float v = __bfloat162float(cb[j * C_]);
            float f = (v - mean) * rstd * gw + gb;
            f = 0.5f * f * (1.0f + erff(f * 0.70710678118654752f));
            feat[j * FEAT_STRIDE + c] = f;
        }
    }
    __syncthreads();

    // ---- Phase C: om = feat @ om_w.T + om_b (wave-cooperative, coalesced) ----
    {
        const int wv = tid >> 6;
        const int lane = tid & 63;
        const int ig = lane >> 4;       // j subgroup 0..3
        const int kk = lane & 15;       // k chunk 0..15
#pragma unroll 1
        for (int bb = 0; bb < 7; ++bb) {
            int slot = bb * 4 + ig;                 // 0..27
            int j = wv + 4 * min(slot, 26);
            const float* wrow = om_w + j * 256 + kk * 4;
            float4 w0v = *(const float4*)(wrow);
            float4 w1v = *(const float4*)(wrow + 64);
            float4 w2v = *(const float4*)(wrow + 128);
            float4 w3v = *(const float4*)(wrow + 192);
            float d[TILE];
#pragma unroll
            for (int pix = 0; pix < TILE; ++pix) {
                const float* fr = feat + pix * FEAT_STRIDE + kk * 4;
                float4 f0 = *(const float4*)(fr);
                float4 f1 = *(const float4*)(fr + 64);
                float4 f2 = *(const float4*)(fr + 128);
                float4 f3 = *(const float4*)(fr + 192);
                d[pix] = f0.x * w0v.x + f0.y * w0v.y + f0.z * w0v.z + f0.w * w0v.w
                       + f1.x * w1v.x + f1.y * w1v.y + f1.z * w1v.z + f1.w * w1v.w
                       + f2.x * w2v.x + f2.y * w2v.y + f2.z * w2v.z + f2.w * w2v.w
                       + f3.x * w3v.x + f3.y * w3v.y + f3.z * w3v.z + f3.w * w3v.w;
            }
#pragma unroll
            for (int m = 1; m <= 8; m <<= 1)
#pragma unroll
                for (int pix = 0; pix < TILE; ++pix)
                    d[pix] += __shfl_xor(d[pix], m, 64);
            if (slot < 27)
                oms[kk * OMS_STRIDE + j] = d[kk] + om_b[j];
        }
    }
    __syncthreads();

    // ---- Phase D1: softmax over P per (pixel, group) * uncertainty ----
    if (tid < TILE * G_) {
        int pix = tid >> 2, g = tid & 3;
        float* m = &oms[pix * OMS_STRIDE + G_ * P_ * 2 + g * P_];
        float mx = m[0];
#pragma unroll
        for (int p = 1; p < P_; ++p) mx = fmaxf(mx, m[p]);
        float e[P_], s = 0.0f;
#pragma unroll
        for (int p = 0; p < P_; ++p) { e[p] = expf(m[p] - mx); s += e[p]; }
        float u = unc[(n * H_ + h) * W_ + w0 + pix];
        float inv = u / s;
#pragma unroll
        for (int p = 0; p < P_; ++p) m[p] = e[p] * inv;
    }
    __syncthreads();

    // ---- Phase D2: build tap table {4 bases, 4 weights} per (pix,g,p) ----
    for (int e = tid; e < TILE * G_ * P_; e += 256) {   // 576 entries
        int pix = e / (G_ * P_);
        int rr = e % (G_ * P_);
        int g = rr / P_, p = rr % P_;
        const float* po = &oms[pix * OMS_STRIDE];
        float ox = po[(g * P_ + p) * 2 + 0];
        float oy = po[(g * P_ + p) * 2 + 1];
        float mk = po[G_ * P_ * 2 + g * P_ + p];
        float sx = (float)(w0 + pix + p / 3) + ox;
        float sy = (float)(h + p % 3) + oy;
        float x0f = floorf(sx), y0f = floorf(sy);
        float wx = sx - x0f, wy = sy - y0f;
        int x0 = (int)x0f - 1, y0 = (int)y0f - 1;       // top-left tap, unpadded
        float fy0 = (y0 >= 0 && y0 < H_) ? 1.0f : 0.0f;
        float fy1 = (y0 + 1 >= 0 && y0 + 1 < H_) ? 1.0f : 0.0f;
        float fx0 = (x0 >= 0 && x0 < W_) ? 1.0f : 0.0f;
        float fx1 = (x0 + 1 >= 0 && x0 + 1 < W_) ? 1.0f : 0.0f;
        int y0c = min(max(y0, 0), H_ - 1), y1c = min(max(y0 + 1, 0), H_ - 1);
        int x0c = min(max(x0, 0), W_ - 1), x1c = min(max(x0 + 1, 0), W_ - 1);
        int4 bs = make_int4((y0c * W_ + x0c) * C_, (y0c * W_ + x1c) * C_,
                            (y1c * W_ + x0c) * C_, (y1c * W_ + x1c) * C_);
        float4 wt = make_float4((1.0f - wy) * (1.0f - wx) * mk * fy0 * fx0,
                                (1.0f - wy) * wx * mk * fy0 * fx1,
                                wy * (1.0f - wx) * mk * fy1 * fx0,
                                wy * wx * mk * fy1 * fx1);
        *(int4*)(table + e * 32) = bs;
        *(float4*)(table + e * 32 + 16) = wt;
    }
    __syncthreads();

    // ---- Phase E: sampling; wave=group, lane=channel; coalesced NHWC taps ----
    {
        const int g = tid >> 6;
        const int lane = tid & 63;
        const __hip_bfloat16* xg = xn + (size_t)n * HW_ * C_ + g * GC_ + lane;
#pragma unroll 1
        for (int pix = 0; pix < TILE; ++pix) {
            const char* te = table + (pix * G_ * P_ + g * P_) * 32;
            float acc = 0.0f;
#pragma unroll 3
            for (int p = 0; p < P_; ++p) {
                int4 bs = *(const int4*)(te + p * 32);
                float4 wt = *(const float4*)(te + p * 32 + 16);
                acc += wt.x * __bfloat162float(xg[bs.x])
                     + wt.y * __bfloat162float(xg[bs.y])
                     + wt.z * __bfloat162float(xg[bs.z])
                     + wt.w * __bfloat162float(xg[bs.w]);
            }
            tbuf[(g * GC_ + lane) * TBUF_STRIDE + pix] = acc;
        }
    }
    __syncthreads();

    // ---- Phase F: full-line coalesced stores (16-lane clusters = one 64B line) ----
    {
        const int px = tid & 15, c0 = tid >> 4;
        float* op = out + (size_t)n * CHW_ + (size_t)h * W_ + w0 + px;
#pragma unroll
        for (int k = 0; k < 16; ++k) {
            int c = c0 * 16 + k;
            op[(size_t)c * HW_] = tbuf[c * TBUF_STRIDE + px];
        }
    }
}

extern "C" void kernel_launch(void* const* d_in, const int* in_sizes, int n_in,
                              void* d_out, int out_size, void* d_ws, size_t ws_size,
                              hipStream_t stream)
{
    const float* x    = (const float*)d_in[0];
    const float* unc  = (const float*)d_in[1];
    const float* dw_w = (const float*)d_in[2];
    const float* dw_b = (const float*)d_in[3];
    const float* gn_w = (const float*)d_in[4];
    const float* gn_b = (const float*)d_in[5];
    const float* om_w = (const float*)d_in[6];
    const float* om_b = (const float*)d_in[7];
    float* out = (float*)d_out;

    float* partials = (float*)d_ws;
    float* stats    = (float*)((char*)d_ws + 12288);
    __hip_bfloat16* xn  = (__hip_bfloat16*)((char*)d_ws + 32768);
    __hip_bfloat16* ctx = (__hip_bfloat16*)((char*)d_ws + 32768 + (size_t)N_ * HW_ * C_ * 2);

    transpose_kernel<<<4608, 256, 0, stream>>>(x, xn);
    conv_ctx_kernel<<<NBLK, 256, 0, stream>>>(xn, dw_w, dw_b, ctx, partials);
    stats_kernel<<<1, 256, 0, stream>>>(partials, stats);
    main_kernel<<<NBLK, 256, 0, stream>>>(xn, unc, ctx, stats,
                                          gn_w, gn_b, om_w, om_b, out);
}

// Round 5
// 189.530 us; speedup vs baseline: 8.6217x; 1.0410x over previous
//
#include <hip/hip_runtime.h>
#include <hip/hip_bf16.h>
#include <math.h>

#define C_   256
#define G_   4
#define P_   9
#define GC_  64
#define H_   96
#define W_   96
#define N_   2
#define HW_  (H_*W_)          // 9216
#define CHW_ (C_*H_*W_)       // 2359296
#define OMC  108              // G*P*3
#define OMR  112              // padded rows of om_w (bf16 copy), rows 108..111 = 0
#define TILE 16               // pixels along w per block
#define NBW  (W_/TILE)        // 6
#define NBLK (N_*H_*NBW)      // 1152
#define XS_ST 58              // shorts per c-row in prep staging (54 used; 29 uints, odd -> conflict-free)
#define FEATB_ST 264          // shorts per pixel row (256 used; multiple of 8 -> 16B-aligned b128)
#define OMS_ST 114
#define TBUF_ST 17

typedef __attribute__((ext_vector_type(8))) short bf16x8;
typedef __attribute__((ext_vector_type(4))) float f32x4;

__device__ __forceinline__ short f2bf(float f) {
    __hip_bfloat16 h = __float2bfloat16(f);
    return *reinterpret_cast<short*>(&h);
}

// ws layout (bytes):
//   [0)      partials: NBLK*2 floats (9216 B)
//   [12288)  stats: 4 floats
//   [16384)  omwb: 112*256 bf16 (57344 B)
//   [81920)  xn  bf16 NHWC (9.44 MB)
//   [+)      ctx bf16 NHWC (9.44 MB)

// ---------------- K0: fused transpose + depthwise conv + partial stats ----------------
__global__ __launch_bounds__(256) void prep_kernel(
    const float* __restrict__ x, const float* __restrict__ dw_w,
    const float* __restrict__ dw_b, __hip_bfloat16* __restrict__ xn,
    __hip_bfloat16* __restrict__ ctx, float* __restrict__ partials)
{
    __shared__ short xs[256 * XS_ST];    // 29696 B: [c][3 rows][18 cols] bf16
    __shared__ float red[8];
    const int tid = threadIdx.x;
    const int b = blockIdx.x;
    const int xcd = b & 7, bidx = b >> 3;
    const int tile = xcd * (NBLK / 8) + bidx;
    const int n = tile / (H_ * NBW);
    const int r = tile % (H_ * NBW);
    const int h = r / NBW;
    const int w0 = (r % NBW) * TILE;

    // stage x[c, h-1..h+1, w0-1..w0+16] f32 -> bf16 LDS, all 256 channels
#pragma unroll 1
    for (int it = 0; it < 54; ++it) {
        int e = tid + it * 256;
        int c = e / 54, q = e - c * 54;
        int r3 = q / 18, i = q - r3 * 18;
        int gy = h - 1 + r3, gx = w0 - 1 + i;
        float val = 0.0f;
        if (gy >= 0 && gy < H_ && gx >= 0 && gx < W_)
            val = x[((size_t)(n * C_ + c) * H_ + gy) * W_ + gx];
        xs[c * XS_ST + q] = f2bf(val);
    }
    __syncthreads();

    const int c = tid;
    float xv[3][18];
    {
        const unsigned* rowp = (const unsigned*)xs + c * (XS_ST / 2);
#pragma unroll
        for (int r3 = 0; r3 < 3; ++r3)
#pragma unroll
            for (int i2 = 0; i2 < 9; ++i2) {
                unsigned u = rowp[r3 * 9 + i2];
                union { unsigned uu; float ff; } lo, hi;
                lo.uu = u << 16; hi.uu = u & 0xffff0000u;
                xv[r3][i2 * 2]     = lo.ff;
                xv[r3][i2 * 2 + 1] = hi.ff;
            }
    }
    float wgt[9];
#pragma unroll
    for (int i = 0; i < 9; ++i) wgt[i] = dw_w[c * 9 + i];
    const float bias = dw_b[c];
    __hip_bfloat16* cb = ctx + ((size_t)(n * H_ + h) * W_ + w0) * C_ + c;
    __hip_bfloat16* xb = xn  + ((size_t)(n * H_ + h) * W_ + w0) * C_ + c;
    float s1 = 0.0f, s2 = 0.0f;
#pragma unroll
    for (int j = 0; j < TILE; ++j) {
        float v = bias;
#pragma unroll
        for (int r3 = 0; r3 < 3; ++r3)
#pragma unroll
            for (int s = 0; s < 3; ++s)
                v += wgt[r3 * 3 + s] * xv[r3][j + s];
        s1 += v; s2 += v * v;
        cb[j * C_] = __float2bfloat16(v);
        xb[j * C_] = __float2bfloat16(xv[1][j + 1]);   // identity re-round of staged bf16
    }
#pragma unroll
    for (int off = 32; off; off >>= 1) {
        s1 += __shfl_down(s1, off, 64);
        s2 += __shfl_down(s2, off, 64);
    }
    const int lane = tid & 63, wv = tid >> 6;
    if (lane == 0) { red[wv] = s1; red[4 + wv] = s2; }
    __syncthreads();
    if (tid == 0) {
        partials[tile * 2 + 0] = red[0] + red[1] + red[2] + red[3];
        partials[tile * 2 + 1] = red[4] + red[5] + red[6] + red[7];
    }
}

// ---------------- K1: reduce partials -> mean/rstd; convert om_w -> bf16 (padded) ----------------
__global__ __launch_bounds__(256) void stats_omw_kernel(
    const float* __restrict__ partials, const float* __restrict__ om_w,
    float* __restrict__ stats, __hip_bfloat16* __restrict__ omwb)
{
    const int tid = threadIdx.x;
    // om_w f32[108][256] -> bf16[112][256], rows 108..111 zero
#pragma unroll 1
    for (int e = tid; e < OMR * 256; e += 256) {
        float v = (e < OMC * 256) ? om_w[e] : 0.0f;
        omwb[e] = __float2bfloat16(v);
    }
    float a0 = 0, b0 = 0, a1 = 0, b1 = 0;
    for (int i = tid; i < NBLK; i += 256) {
        float p1 = partials[i * 2 + 0], p2 = partials[i * 2 + 1];
        if (i < NBLK / 2) { a0 += p1; b0 += p2; }
        else              { a1 += p1; b1 += p2; }
    }
#pragma unroll
    for (int off = 32; off; off >>= 1) {
        a0 += __shfl_down(a0, off, 64); b0 += __shfl_down(b0, off, 64);
        a1 += __shfl_down(a1, off, 64); b1 += __shfl_down(b1, off, 64);
    }
    __shared__ float red[4][4];
    const int lane = tid & 63, wv = tid >> 6;
    if (lane == 0) { red[wv][0] = a0; red[wv][1] = b0; red[wv][2] = a1; red[wv][3] = b1; }
    __syncthreads();
    if (tid == 0) {
        float A0 = red[0][0] + red[1][0] + red[2][0] + red[3][0];
        float B0 = red[0][1] + red[1][1] + red[2][1] + red[3][1];
        float A1 = red[0][2] + red[1][2] + red[2][2] + red[3][2];
        float B1 = red[0][3] + red[1][3] + red[2][3] + red[3][3];
        float m0 = A0 * (1.0f / (float)CHW_);
        float v0 = B0 * (1.0f / (float)CHW_) - m0 * m0;
        float m1 = A1 * (1.0f / (float)CHW_);
        float v1 = B1 * (1.0f / (float)CHW_) - m1 * m1;
        stats[0] = m0; stats[1] = rsqrtf(v0 + 1e-5f);
        stats[2] = m1; stats[3] = rsqrtf(v1 + 1e-5f);
    }
}

// ---------------- K2: norm+gelu -> MFMA om matmul -> softmax -> table -> sampling ----------------
__global__ __launch_bounds__(256, 5) void main_kernel(
    const __hip_bfloat16* __restrict__ xn, const float* __restrict__ unc,
    const __hip_bfloat16* __restrict__ ctx, const float* __restrict__ stats,
    const float* __restrict__ gn_w, const float* __restrict__ gn_b,
    const __hip_bfloat16* __restrict__ omwb, const float* __restrict__ om_b,
    float* __restrict__ out)
{
    // overlay plan (time-disjoint):
    //   [0,8448)      featb  short[16][264]     (Phase B->C)
    //   [0,4608)      tidx   uint2[576]         (Phase D2->E)
    //   [4608,13824)  twt    float4[576]        (Phase D2->E)
    //   [13824,21120) oms    f32[16][114]       (Phase C->D2)
    //   [13824,31232) tbuf   f32[256][17]       (Phase E->F)
    __shared__ __align__(16) char smem[31232];
    short* featb = (short*)smem;
    uint2* tidx  = (uint2*)smem;
    float4* twt  = (float4*)(smem + 4608);
    float* oms   = (float*)(smem + 13824);
    float* tbuf  = (float*)(smem + 13824);

    const int tid = threadIdx.x;
    const int b = blockIdx.x;
    const int xcd = b & 7, bidx = b >> 3;
    const int tile = xcd * (NBLK / 8) + bidx;   // xcd owns contiguous rows -> L2 halo reuse
    const int n = tile / (H_ * NBW);
    const int rem = tile % (H_ * NBW);
    const int h = rem / NBW;
    const int w0 = (rem % NBW) * TILE;

    // ---- Phase B: ctx load + groupnorm + exact GELU -> feat bf16 (thread = channel) ----
    {
        const int c = tid;
        const float mean = stats[n * 2 + 0];
        const float rstd = stats[n * 2 + 1];
        const float gw = gn_w[c], gb = gn_b[c];
        const __hip_bfloat16* cb = ctx + ((size_t)(n * H_ + h) * W_ + w0) * C_ + c;
#pragma unroll
        for (int j = 0; j < TILE; ++j) {
            float v = __bfloat162float(cb[j * C_]);
            float f = (v - mean) * rstd * gw + gb;
            f = 0.5f * f * (1.0f + erff(f * 0.70710678118654752f));
            featb[j * FEATB_ST + c] = f2bf(f);
        }
    }
    __syncthreads();

    // ---- Phase C: om = feat @ om_w.T + om_b via MFMA 16x16x32 bf16 ----
    // A[m][k]: m=lane&15 (pixel), k=quad*8+j  -> b128 from featb row m
    // B[k][n]: n=lane&15 (out col), k=quad*8+j -> b128 from omwb row (n0+n)
    // D[m][n]: row m = quad*4+reg, col n = lane&15   [m89/m120 layouts]
    {
        const int wv = tid >> 6, lane = tid & 63;
        const int mrow = lane & 15, quad = lane >> 4;
        const short* fb  = featb + mrow * FEATB_ST;
        const short* wb0 = (const short*)omwb + (wv * 16 + mrow) * 256;
        const short* wb1 = (const short*)omwb + ((wv + 4) * 16 + mrow) * 256;
        f32x4 acc0 = {0.f, 0.f, 0.f, 0.f}, acc1 = {0.f, 0.f, 0.f, 0.f};
#pragma unroll
        for (int ks = 0; ks < 8; ++ks) {
            const int k = ks * 32 + quad * 8;
            bf16x8 a  = *(const bf16x8*)(fb + k);
            bf16x8 b0 = *(const bf16x8*)(wb0 + k);
            acc0 = __builtin_amdgcn_mfma_f32_16x16x32_bf16(a, b0, acc0, 0, 0, 0);
            if (wv < 3) {
                bf16x8 b1 = *(const bf16x8*)(wb1 + k);
                acc1 = __builtin_amdgcn_mfma_f32_16x16x32_bf16(a, b1, acc1, 0, 0, 0);
            }
        }
        const int j0 = wv * 16 + mrow;
        const float ob0 = om_b[j0];
#pragma unroll
        for (int rg = 0; rg < 4; ++rg)
            oms[(quad * 4 + rg) * OMS_ST + j0] = acc0[rg] + ob0;
        if (wv < 3) {
            const int j1 = (wv + 4) * 16 + mrow;
            if (j1 < OMC) {
                const float ob1 = om_b[j1];
#pragma unroll
                for (int rg = 0; rg < 4; ++rg)
                    oms[(quad * 4 + rg) * OMS_ST + j1] = acc1[rg] + ob1;
            }
        }
    }
    __syncthreads();

    // ---- Phase D1: softmax over P per (pixel, group) * uncertainty ----
    if (tid < TILE * G_) {
        int pix = tid >> 2, g = tid & 3;
        float* m = &oms[pix * OMS_ST + G_ * P_ * 2 + g * P_];
        float mx = m[0];
#pragma unroll
        for (int p = 1; p < P_; ++p) mx = fmaxf(mx, m[p]);
        float e[P_], s = 0.0f;
#pragma unroll
        for (int p = 0; p < P_; ++p) { e[p] = expf(m[p] - mx); s += e[p]; }
        float u = unc[(n * H_ + h) * W_ + w0 + pix];
        float inv = u / s;
#pragma unroll
        for (int p = 0; p < P_; ++p) m[p] = e[p] * inv;
    }
    __syncthreads();

    // ---- Phase D2: build tap table (SoA: packed u16 pixel indices + f32 weights) ----
    for (int e = tid; e < TILE * G_ * P_; e += 256) {   // 576 entries
        int pix = e / (G_ * P_);
        int rr = e - pix * (G_ * P_);
        int g = rr / P_, p = rr - g * P_;
        const float* po = &oms[pix * OMS_ST];
        float ox = po[(g * P_ + p) * 2 + 0];
        float oy = po[(g * P_ + p) * 2 + 1];
        float mk = po[G_ * P_ * 2 + g * P_ + p];
        float sx = (float)(w0 + pix + p / 3) + ox;
        float sy = (float)(h + p % 3) + oy;
        float x0f = floorf(sx), y0f = floorf(sy);
        float wx = sx - x0f, wy = sy - y0f;
        int x0 = (int)x0f - 1, y0 = (int)y0f - 1;       // top-left tap, unpadded
        float fy0 = (y0 >= 0 && y0 < H_) ? 1.0f : 0.0f;
        float fy1 = (y0 + 1 >= 0 && y0 + 1 < H_) ? 1.0f : 0.0f;
        float fx0 = (x0 >= 0 && x0 < W_) ? 1.0f : 0.0f;
        float fx1 = (x0 + 1 >= 0 && x0 + 1 < W_) ? 1.0f : 0.0f;
        int y0c = min(max(y0, 0), H_ - 1), y1c = min(max(y0 + 1, 0), H_ - 1);
        int x0c = min(max(x0, 0), W_ - 1), x1c = min(max(x0 + 1, 0), W_ - 1);
        unsigned i00 = (unsigned)(y0c * W_ + x0c), i01 = (unsigned)(y0c * W_ + x1c);
        unsigned i10 = (unsigned)(y1c * W_ + x0c), i11 = (unsigned)(y1c * W_ + x1c);
        tidx[e] = make_uint2(i00 | (i01 << 16), i10 | (i11 << 16));
        twt[e] = make_float4((1.0f - wy) * (1.0f - wx) * mk * fy0 * fx0,
                             (1.0f - wy) * wx * mk * fy0 * fx1,
                             wy * (1.0f - wx) * mk * fy1 * fx0,
                             wy * wx * mk * fy1 * fx1);
    }
    __syncthreads();

    // ---- Phase E: sampling; wave=group, lane=channel; coalesced NHWC taps ----
    {
        const int g = tid >> 6;
        const int lane = tid & 63;
        const __hip_bfloat16* xg = xn + (size_t)n * HW_ * C_ + g * GC_ + lane;
#pragma unroll 1
        for (int pix = 0; pix < TILE; ++pix) {
            const int te = pix * G_ * P_ + g * P_;
            float acc = 0.0f;
#pragma unroll 3
            for (int p = 0; p < P_; ++p) {
                uint2 bi = tidx[te + p];
                float4 wt = twt[te + p];
                acc += wt.x * __bfloat162float(xg[(bi.x & 0xffffu) << 8])
                     + wt.y * __bfloat162float(xg[(bi.x >> 16) << 8])
                     + wt.z * __bfloat162float(xg[(bi.y & 0xffffu) << 8])
                     + wt.w * __bfloat162float(xg[(bi.y >> 16) << 8]);
            }
            tbuf[(g * GC_ + lane) * TBUF_ST + pix] = acc;
        }
    }
    __syncthreads();

    // ---- Phase F: full-line coalesced stores ----
    {
        const int px = tid & 15, c0 = tid >> 4;
        float* op = out + (size_t)n * CHW_ + (size_t)h * W_ + w0 + px;
#pragma unroll
        for (int k = 0; k < 16; ++k) {
            int c = c0 * 16 + k;
            op[(size_t)c * HW_] = tbuf[c * TBUF_ST + px];
        }
    }
}

extern "C" void kernel_launch(void* const* d_in, const int* in_sizes, int n_in,
                              void* d_out, int out_size, void* d_ws, size_t ws_size,
                              hipStream_t stream)
{
    const float* x    = (const float*)d_in[0];
    const float* unc  = (const float*)d_in[1];
    const float* dw_w = (const float*)d_in[2];
    const float* dw_b = (const float*)d_in[3];
    const float* gn_w = (const float*)d_in[4];
    const float* gn_b = (const float*)d_in[5];
    const float* om_w = (const float*)d_in[6];
    const float* om_b = (const float*)d_in[7];
    float* out = (float*)d_out;

    float* partials      = (float*)d_ws;
    float* stats         = (float*)((char*)d_ws + 12288);
    __hip_bfloat16* omwb = (__hip_bfloat16*)((char*)d_ws + 16384);
    __hip_bfloat16* xn   = (__hip_bfloat16*)((char*)d_ws + 81920);
    __hip_bfloat16* ctx  = xn + (size_t)N_ * HW_ * C_;

    prep_kernel<<<NBLK, 256, 0, stream>>>(x, dw_w, dw_b, xn, ctx, partials);
    stats_omw_kernel<<<1, 256, 0, stream>>>(partials, om_w, stats, omwb);
    main_kernel<<<NBLK, 256, 0, stream>>>(xn, unc, ctx, stats,
                                          gn_w, gn_b, omwb, om_b, out);
}

// Round 6
// 142.429 us; speedup vs baseline: 11.4729x; 1.3307x over previous
//
#include <hip/hip_runtime.h>
#include <hip/hip_bf16.h>
#include <math.h>

#define C_   256
#define G_   4
#define P_   9
#define GC_  64
#define H_   96
#define W_   96
#define N_   2
#define HW_  (H_*W_)          // 9216
#define CHW_ (C_*H_*W_)       // 2359296
#define OMC  108              // G*P*3
#define OMR  112              // padded rows of om_w bf16 copy
#define TILE 16               // pixels along w per block (main)
#define NBW  (W_/TILE)        // 6
#define NBLK (N_*H_*NBW)      // 1152 main tiles
#define NCONV 1536            // prep conv blocks: N*H*(C/32)
#define NOMW  16              // prep tail blocks converting om_w
#define R_ST  99              // LDS row stride (f32) in prep
#define C_ST  (3*R_ST)        // 297, odd -> conflict-free across c lanes
#define FEATB_ST 264          // shorts per pixel row in main
#define OMS_ST 114
#define TBUF_ST 17

typedef __attribute__((ext_vector_type(8))) short bf16x8;
typedef __attribute__((ext_vector_type(4))) float f32x4;

__device__ __forceinline__ short f2bf(float f) {
    __hip_bfloat16 h = __float2bfloat16(f);
    return *reinterpret_cast<short*>(&h);
}

// ws layout (bytes):
//   [0)      partials: NCONV*2 floats (12288 B)
//   [12288)  stats: 4 floats
//   [16384)  omwb: 112*256 bf16 (57344 B)
//   [81920)  xn  bf16 NHWC (9.44 MB)
//   [+)      ctx bf16 NHWC (9.44 MB)

// ---------------- K0: prep — conv blocks (NCHW-coalesced) + omwb tail blocks ----------------
__global__ __launch_bounds__(256) void prep_kernel(
    const float* __restrict__ x, const float* __restrict__ dw_w,
    const float* __restrict__ dw_b, const float* __restrict__ om_w,
    __hip_bfloat16* __restrict__ xn, __hip_bfloat16* __restrict__ ctx,
    __hip_bfloat16* __restrict__ omwb, float* __restrict__ partials)
{
    const int b = blockIdx.x;
    const int tid = threadIdx.x;

    if (b >= NCONV) {
        // ---- om_w f32[108][256] -> omwb bf16[112][256] (rows 108..111 zero) ----
        const int bb = b - NCONV;                    // 0..15
        const float4* src = (const float4*)om_w;     // 6912 float4 valid
        ushort4* dst = (ushort4*)omwb;               // 7168 ushort4 total
#pragma unroll
        for (int it = 0; it < 2; ++it) {
            int i = tid + it * 256;
            if (i < 448) {
                int fi = bb * 448 + i;
                float4 v = (fi < 6912) ? src[fi] : make_float4(0.f, 0.f, 0.f, 0.f);
                ushort4 u;
                u.x = (unsigned short)f2bf(v.x); u.y = (unsigned short)f2bf(v.y);
                u.z = (unsigned short)f2bf(v.z); u.w = (unsigned short)f2bf(v.w);
                dst[fi] = u;
            }
        }
        return;
    }

    // ---- conv block: 32 channels x one image row h ----
    __shared__ float xs[32 * C_ST];   // 38016 B: [c][r=3][cols 0..97], col = w+1
    __shared__ float red[8];
    const int xcd = b & 7, i = b >> 3;           // i in [0,192)
    const int nh = xcd * 24 + (i >> 3);          // xcd owns 24 contiguous rows
    const int ct = i & 7;
    const int n = nh / H_, h = nh % H_;
    const int c0 = ct * 32;

    // zero halo columns (w=-1 -> col 0, w=96 -> col 97)
    if (tid < 96) {
        int c = tid / 3, r = tid % 3;
        xs[c * C_ST + r * R_ST + 0] = 0.0f;
        xs[c * C_ST + r * R_ST + 97] = 0.0f;
    }
    // stage x[c0..c0+32, h-1..h+1, 0..96) via coalesced float4
#pragma unroll
    for (int it = 0; it < 9; ++it) {
        int idx = tid + it * 256;                // 0..2303
        int row = idx / 24;                      // c*3+r
        int col = idx % 24;                      // float4 col
        int c = row / 3, r = row % 3;
        int gy = h - 1 + r;
        float4 v = make_float4(0.f, 0.f, 0.f, 0.f);
        if (gy >= 0 && gy < H_)
            v = *(const float4*)&x[(size_t)(n * C_ + c0 + c) * HW_ + gy * W_ + col * 4];
        float* dstp = &xs[c * C_ST + r * R_ST + 1 + col * 4];
        dstp[0] = v.x; dstp[1] = v.y; dstp[2] = v.z; dstp[3] = v.w;
    }
    __syncthreads();

    // thread = (wslot, c): c = tid&31, 12 outputs at w = wslot*12 + j
    const int c = tid & 31, wslot = tid >> 5;
    const int W0 = wslot * 12;
    float wgt[9];
#pragma unroll
    for (int q = 0; q < 9; ++q) wgt[q] = dw_w[(c0 + c) * 9 + q];
    const float bias = dw_b[c0 + c];

    float seg[3][14];
#pragma unroll
    for (int r = 0; r < 3; ++r)
#pragma unroll
        for (int k = 0; k < 14; ++k)
            seg[r][k] = xs[c * C_ST + r * R_ST + W0 + k];

    __hip_bfloat16* cb = ctx + ((size_t)nh * W_ + W0) * C_ + c0 + c;
    __hip_bfloat16* xb = xn  + ((size_t)nh * W_ + W0) * C_ + c0 + c;
    float s1 = 0.0f, s2 = 0.0f;
#pragma unroll
    for (int j = 0; j < 12; ++j) {
        float v = bias;
#pragma unroll
        for (int r = 0; r < 3; ++r)
            v += wgt[r * 3 + 0] * seg[r][j]
               + wgt[r * 3 + 1] * seg[r][j + 1]
               + wgt[r * 3 + 2] * seg[r][j + 2];
        s1 += v; s2 += v * v;
        cb[j * C_] = __float2bfloat16(v);
        xb[j * C_] = __float2bfloat16(seg[1][j + 1]);
    }
#pragma unroll
    for (int off = 32; off; off >>= 1) {
        s1 += __shfl_down(s1, off, 64);
        s2 += __shfl_down(s2, off, 64);
    }
    const int lane = tid & 63, wv = tid >> 6;
    if (lane == 0) { red[wv] = s1; red[4 + wv] = s2; }
    __syncthreads();
    if (tid == 0) {
        partials[b * 2 + 0] = red[0] + red[1] + red[2] + red[3];
        partials[b * 2 + 1] = red[4] + red[5] + red[6] + red[7];
    }
}

// ---------------- K1: reduce partials -> mean/rstd per n ----------------
__global__ __launch_bounds__(256) void stats_kernel(
    const float* __restrict__ partials, float* __restrict__ stats)
{
    const int tid = threadIdx.x;
    float a0 = 0, b0 = 0, a1 = 0, b1 = 0;
#pragma unroll
    for (int it = 0; it < 6; ++it) {
        int i = tid + it * 256;                       // conv block id
        float p1 = partials[i * 2 + 0], p2 = partials[i * 2 + 1];
        if (((i & 7) >> 2) == 0) { a0 += p1; b0 += p2; }
        else                     { a1 += p1; b1 += p2; }
    }
#pragma unroll
    for (int off = 32; off; off >>= 1) {
        a0 += __shfl_down(a0, off, 64); b0 += __shfl_down(b0, off, 64);
        a1 += __shfl_down(a1, off, 64); b1 += __shfl_down(b1, off, 64);
    }
    __shared__ float red[4][4];
    const int lane = tid & 63, wv = tid >> 6;
    if (lane == 0) { red[wv][0] = a0; red[wv][1] = b0; red[wv][2] = a1; red[wv][3] = b1; }
    __syncthreads();
    if (tid == 0) {
        float A0 = red[0][0] + red[1][0] + red[2][0] + red[3][0];
        float B0 = red[0][1] + red[1][1] + red[2][1] + red[3][1];
        float A1 = red[0][2] + red[1][2] + red[2][2] + red[3][2];
        float B1 = red[0][3] + red[1][3] + red[2][3] + red[3][3];
        float m0 = A0 * (1.0f / (float)CHW_);
        float v0 = B0 * (1.0f / (float)CHW_) - m0 * m0;
        float m1 = A1 * (1.0f / (float)CHW_);
        float v1 = B1 * (1.0f / (float)CHW_) - m1 * m1;
        stats[0] = m0; stats[1] = rsqrtf(v0 + 1e-5f);
        stats[2] = m1; stats[3] = rsqrtf(v1 + 1e-5f);
    }
}

// ---------------- K2: norm+gelu -> MFMA om matmul -> softmax -> table -> sampling ----------------
__global__ __launch_bounds__(256, 5) void main_kernel(
    const __hip_bfloat16* __restrict__ xn, const float* __restrict__ unc,
    const __hip_bfloat16* __restrict__ ctx, const float* __restrict__ stats,
    const float* __restrict__ gn_w, const float* __restrict__ gn_b,
    const __hip_bfloat16* __restrict__ omwb, const float* __restrict__ om_b,
    float* __restrict__ out)
{
    // overlay plan (time-disjoint):
    //   [0,8448)      featb  short[16][264]     (Phase B->C)
    //   [0,4608)      tidx   uint2[576]         (Phase D2->E)
    //   [4608,13824)  twt    float4[576]        (Phase D2->E)
    //   [13824,21120) oms    f32[16][114]       (Phase C->D2)
    //   [13824,31232) tbuf   f32[256][17]       (Phase E->F)
    __shared__ __align__(16) char smem[31232];
    short* featb = (short*)smem;
    uint2* tidx  = (uint2*)smem;
    float4* twt  = (float4*)(smem + 4608);
    float* oms   = (float*)(smem + 13824);
    float* tbuf  = (float*)(smem + 13824);

    const int tid = threadIdx.x;
    const int b = blockIdx.x;
    const int xcd = b & 7, bidx = b >> 3;
    const int tile = xcd * (NBLK / 8) + bidx;   // xcd owns contiguous rows -> L2 halo reuse
    const int n = tile / (H_ * NBW);
    const int rem = tile % (H_ * NBW);
    const int h = rem / NBW;
    const int w0 = (rem % NBW) * TILE;

    // ---- Phase B: ctx load + groupnorm + exact GELU -> feat bf16 (thread = channel) ----
    {
        const int c = tid;
        const float mean = stats[n * 2 + 0];
        const float rstd = stats[n * 2 + 1];
        const float gw = gn_w[c], gb = gn_b[c];
        const __hip_bfloat16* cb = ctx + ((size_t)(n * H_ + h) * W_ + w0) * C_ + c;
#pragma unroll
        for (int j = 0; j < TILE; ++j) {
            float v = __bfloat162float(cb[j * C_]);
            float f = (v - mean) * rstd * gw + gb;
            f = 0.5f * f * (1.0f + erff(f * 0.70710678118654752f));
            featb[j * FEATB_ST + c] = f2bf(f);
        }
    }
    __syncthreads();

    // ---- Phase C: om = feat @ om_w.T + om_b via MFMA 16x16x32 bf16 ----
    {
        const int wv = tid >> 6, lane = tid & 63;
        const int mrow = lane & 15, quad = lane >> 4;
        const short* fb  = featb + mrow * FEATB_ST;
        const short* wb0 = (const short*)omwb + (wv * 16 + mrow) * 256;
        const short* wb1 = (const short*)omwb + ((wv + 4) * 16 + mrow) * 256;
        f32x4 acc0 = {0.f, 0.f, 0.f, 0.f}, acc1 = {0.f, 0.f, 0.f, 0.f};
#pragma unroll
        for (int ks = 0; ks < 8; ++ks) {
            const int k = ks * 32 + quad * 8;
            bf16x8 a  = *(const bf16x8*)(fb + k);
            bf16x8 b0 = *(const bf16x8*)(wb0 + k);
            acc0 = __builtin_amdgcn_mfma_f32_16x16x32_bf16(a, b0, acc0, 0, 0, 0);
            if (wv < 3) {
                bf16x8 b1 = *(const bf16x8*)(wb1 + k);
                acc1 = __builtin_amdgcn_mfma_f32_16x16x32_bf16(a, b1, acc1, 0, 0, 0);
            }
        }
        const int j0 = wv * 16 + mrow;
        const float ob0 = om_b[j0];
#pragma unroll
        for (int rg = 0; rg < 4; ++rg)
            oms[(quad * 4 + rg) * OMS_ST + j0] = acc0[rg] + ob0;
        if (wv < 3) {
            const int j1 = (wv + 4) * 16 + mrow;
            if (j1 < OMC) {
                const float ob1 = om_b[j1];
#pragma unroll
                for (int rg = 0; rg < 4; ++rg)
                    oms[(quad * 4 + rg) * OMS_ST + j1] = acc1[rg] + ob1;
            }
        }
    }
    __syncthreads();

    // ---- Phase D1: softmax over P per (pixel, group) * uncertainty ----
    if (tid < TILE * G_) {
        int pix = tid >> 2, g = tid & 3;
        float* m = &oms[pix * OMS_ST + G_ * P_ * 2 + g * P_];
        float mx = m[0];
#pragma unroll
        for (int p = 1; p < P_; ++p) mx = fmaxf(mx, m[p]);
        float e[P_], s = 0.0f;
#pragma unroll
        for (int p = 0; p < P_; ++p) { e[p] = expf(m[p] - mx); s += e[p]; }
        float u = unc[(n * H_ + h) * W_ + w0 + pix];
        float inv = u / s;
#pragma unroll
        for (int p = 0; p < P_; ++p) m[p] = e[p] * inv;
    }
    __syncthreads();

    // ---- Phase D2: build tap table (SoA: packed u16 pixel indices + f32 weights) ----
    for (int e = tid; e < TILE * G_ * P_; e += 256) {   // 576 entries
        int pix = e / (G_ * P_);
        int rr = e - pix * (G_ * P_);
        int g = rr / P_, p = rr - g * P_;
        const float* po = &oms[pix * OMS_ST];
        float ox = po[(g * P_ + p) * 2 + 0];
        float oy = po[(g * P_ + p) * 2 + 1];
        float mk = po[G_ * P_ * 2 + g * P_ + p];
        float sx = (float)(w0 + pix + p / 3) + ox;
        float sy = (float)(h + p % 3) + oy;
        float x0f = floorf(sx), y0f = floorf(sy);
        float wx = sx - x0f, wy = sy - y0f;
        int x0 = (int)x0f - 1, y0 = (int)y0f - 1;       // top-left tap, unpadded
        float fy0 = (y0 >= 0 && y0 < H_) ? 1.0f : 0.0f;
        float fy1 = (y0 + 1 >= 0 && y0 + 1 < H_) ? 1.0f : 0.0f;
        float fx0 = (x0 >= 0 && x0 < W_) ? 1.0f : 0.0f;
        float fx1 = (x0 + 1 >= 0 && x0 + 1 < W_) ? 1.0f : 0.0f;
        int y0c = min(max(y0, 0), H_ - 1), y1c = min(max(y0 + 1, 0), H_ - 1);
        int x0c = min(max(x0, 0), W_ - 1), x1c = min(max(x0 + 1, 0), W_ - 1);
        unsigned i00 = (unsigned)(y0c * W_ + x0c), i01 = (unsigned)(y0c * W_ + x1c);
        unsigned i10 = (unsigned)(y1c * W_ + x0c), i11 = (unsigned)(y1c * W_ + x1c);
        tidx[e] = make_uint2(i00 | (i01 << 16), i10 | (i11 << 16));
        twt[e] = make_float4((1.0f - wy) * (1.0f - wx) * mk * fy0 * fx0,
                             (1.0f - wy) * wx * mk * fy0 * fx1,
                             wy * (1.0f - wx) * mk * fy1 * fx0,
                             wy * wx * mk * fy1 * fx1);
    }
    __syncthreads();

    // ---- Phase E: sampling; wave=group, lane=channel; coalesced NHWC taps ----
    {
        const int g = tid >> 6;
        const int lane = tid & 63;
        const __hip_bfloat16* xg = xn + (size_t)n * HW_ * C_ + g * GC_ + lane;
#pragma unroll 1
        for (int pix = 0; pix < TILE; ++pix) {
            const int te = pix * G_ * P_ + g * P_;
            float acc = 0.0f;
#pragma unroll
            for (int p = 0; p < P_; ++p) {
                uint2 bi = tidx[te + p];
                float4 wt = twt[te + p];
                acc += wt.x * __bfloat162float(xg[(bi.x & 0xffffu) << 8])
                     + wt.y * __bfloat162float(xg[(bi.x >> 16) << 8])
                     + wt.z * __bfloat162float(xg[(bi.y & 0xffffu) << 8])
                     + wt.w * __bfloat162float(xg[(bi.y >> 16) << 8]);
            }
            tbuf[(g * GC_ + lane) * TBUF_ST + pix] = acc;
        }
    }
    __syncthreads();

    // ---- Phase F: full-line coalesced stores ----
    {
        const int px = tid & 15, c0 = tid >> 4;
        float* op = out + (size_t)n * CHW_ + (size_t)h * W_ + w0 + px;
#pragma unroll
        for (int k = 0; k < 16; ++k) {
            int c = c0 * 16 + k;
            op[(size_t)c * HW_] = tbuf[c * TBUF_ST + px];
        }
    }
}

extern "C" void kernel_launch(void* const* d_in, const int* in_sizes, int n_in,
                              void* d_out, int out_size, void* d_ws, size_t ws_size,
                              hipStream_t stream)
{
    const float* x    = (const float*)d_in[0];
    const float* unc  = (const float*)d_in[1];
    const float* dw_w = (const float*)d_in[2];
    const float* dw_b = (const float*)d_in[3];
    const float* gn_w = (const float*)d_in[4];
    const float* gn_b = (const float*)d_in[5];
    const float* om_w = (const float*)d_in[6];
    const float* om_b = (const float*)d_in[7];
    float* out = (float*)d_out;

    float* partials      = (float*)d_ws;
    float* stats         = (float*)((char*)d_ws + 12288);
    __hip_bfloat16* omwb = (__hip_bfloat16*)((char*)d_ws + 16384);
    __hip_bfloat16* xn   = (__hip_bfloat16*)((char*)d_ws + 81920);
    __hip_bfloat16* ctx  = xn + (size_t)N_ * HW_ * C_;

    prep_kernel<<<NCONV + NOMW, 256, 0, stream>>>(x, dw_w, dw_b, om_w, xn, ctx, omwb, partials);
    stats_kernel<<<1, 256, 0, stream>>>(partials, stats);
    main_kernel<<<NBLK, 256, 0, stream>>>(xn, unc, ctx, stats,
                                          gn_w, gn_b, omwb, om_b, out);
}

// Round 10
// 139.796 us; speedup vs baseline: 11.6890x; 1.0188x over previous
//
#include <hip/hip_runtime.h>
#include <hip/hip_bf16.h>
#include <hip/hip_fp16.h>
#include <math.h>

#define C_   256
#define G_   4
#define P_   9
#define GC_  64
#define H_   96
#define W_   96
#define N_   2
#define HW_  (H_*W_)          // 9216
#define CHW_ (C_*H_*W_)       // 2359296
#define OMC  108              // G*P*3
#define OMR  112              // padded rows of om_w bf16 copy
#define TILE 16               // pixels along w per block (main)
#define NBW  (W_/TILE)        // 6
#define NBLK (N_*H_*NBW)      // 1152 main tiles
#define NCONV 1536            // prep conv blocks: N*H*(C/32)
#define NOMW  16              // prep tail blocks converting om_w
#define R_ST  99              // LDS row stride (f32) in prep
#define C_ST  (3*R_ST)        // 297, odd -> conflict-free across c lanes
#define FEATB_ST 264          // shorts per pixel row in main
#define OMS_ST 114
#define TBUF_ST 17

typedef __attribute__((ext_vector_type(8))) short bf16x8;
typedef __attribute__((ext_vector_type(4))) float f32x4;

__device__ __forceinline__ short f2bf(float f) {
    __hip_bfloat16 h = __float2bfloat16(f);
    return *reinterpret_cast<short*>(&h);
}

// ws layout (bytes):
//   [0)      partials: NCONV*2 floats (12288 B), deterministic per-block sums
//   [12288)  stats: 4 floats {mean0, rstd0, mean1, rstd1}
//   [16384)  omwb: 112*256 bf16 (57344 B)
//   [81920)  xn  bf16 NHWC (9.44 MB)
//   [+)      ctx bf16 NHWC (9.44 MB)
// NOTE: no atomics anywhere; this is the R5 structure, HW-validated PASS.

// ---------------- K0: prep — conv blocks (NCHW-coalesced) + omwb tail blocks ----------------
__global__ __launch_bounds__(256) void prep_kernel(
    const float* __restrict__ x, const float* __restrict__ dw_w,
    const float* __restrict__ dw_b, const float* __restrict__ om_w,
    __hip_bfloat16* __restrict__ xn, __hip_bfloat16* __restrict__ ctx,
    __hip_bfloat16* __restrict__ omwb, float* __restrict__ partials)
{
    const int b = blockIdx.x;
    const int tid = threadIdx.x;

    if (b >= NCONV) {
        // ---- om_w f32[108][256] -> omwb bf16[112][256] (rows 108..111 zero) ----
        const int bb = b - NCONV;                    // 0..15
        const float4* src = (const float4*)om_w;     // 6912 float4 valid
        ushort4* dst = (ushort4*)omwb;               // 7168 ushort4 total
#pragma unroll
        for (int it = 0; it < 2; ++it) {
            int i = tid + it * 256;
            if (i < 448) {
                int fi = bb * 448 + i;
                float4 v = (fi < 6912) ? src[fi] : make_float4(0.f, 0.f, 0.f, 0.f);
                ushort4 u;
                u.x = (unsigned short)f2bf(v.x); u.y = (unsigned short)f2bf(v.y);
                u.z = (unsigned short)f2bf(v.z); u.w = (unsigned short)f2bf(v.w);
                dst[fi] = u;
            }
        }
        return;
    }

    // ---- conv block: 32 channels x one image row h ----
    __shared__ float xs[32 * C_ST];   // 38016 B: [c][r=3][cols 0..97], col = w+1
    __shared__ float red[8];
    const int xcd = b & 7, i = b >> 3;           // i in [0,192)
    const int nh = xcd * 24 + (i >> 3);          // xcd owns 24 contiguous rows
    const int ct = i & 7;
    const int n = nh / H_, h = nh % H_;
    const int c0 = ct * 32;

    // zero halo columns (w=-1 -> col 0, w=96 -> col 97)
    if (tid < 96) {
        int c = tid / 3, r = tid % 3;
        xs[c * C_ST + r * R_ST + 0] = 0.0f;
        xs[c * C_ST + r * R_ST + 97] = 0.0f;
    }
    // stage x[c0..c0+32, h-1..h+1, 0..96) via coalesced float4
#pragma unroll
    for (int it = 0; it < 9; ++it) {
        int idx = tid + it * 256;                // 0..2303
        int row = idx / 24;                      // c*3+r
        int col = idx % 24;                      // float4 col
        int c = row / 3, r = row % 3;
        int gy = h - 1 + r;
        float4 v = make_float4(0.f, 0.f, 0.f, 0.f);
        if (gy >= 0 && gy < H_)
            v = *(const float4*)&x[(size_t)(n * C_ + c0 + c) * HW_ + gy * W_ + col * 4];
        float* dstp = &xs[c * C_ST + r * R_ST + 1 + col * 4];
        dstp[0] = v.x; dstp[1] = v.y; dstp[2] = v.z; dstp[3] = v.w;
    }
    __syncthreads();

    // thread = (wslot, c): c = tid&31, 12 outputs at w = wslot*12 + j
    const int c = tid & 31, wslot = tid >> 5;
    const int W0 = wslot * 12;
    float wgt[9];
#pragma unroll
    for (int q = 0; q < 9; ++q) wgt[q] = dw_w[(c0 + c) * 9 + q];
    const float bias = dw_b[c0 + c];

    float seg[3][14];
#pragma unroll
    for (int r = 0; r < 3; ++r)
#pragma unroll
        for (int k = 0; k < 14; ++k)
            seg[r][k] = xs[c * C_ST + r * R_ST + W0 + k];

    __hip_bfloat16* cb = ctx + ((size_t)nh * W_ + W0) * C_ + c0 + c;
    __hip_bfloat16* xb = xn  + ((size_t)nh * W_ + W0) * C_ + c0 + c;
    float s1 = 0.0f, s2 = 0.0f;
#pragma unroll
    for (int j = 0; j < 12; ++j) {
        float v = bias;
#pragma unroll
        for (int r = 0; r < 3; ++r)
            v += wgt[r * 3 + 0] * seg[r][j]
               + wgt[r * 3 + 1] * seg[r][j + 1]
               + wgt[r * 3 + 2] * seg[r][j + 2];
        s1 += v; s2 += v * v;
        cb[j * C_] = __float2bfloat16(v);
        xb[j * C_] = __float2bfloat16(seg[1][j + 1]);
    }
#pragma unroll
    for (int off = 32; off; off >>= 1) {
        s1 += __shfl_down(s1, off, 64);
        s2 += __shfl_down(s2, off, 64);
    }
    const int lane = tid & 63, wv = tid >> 6;
    if (lane == 0) { red[wv] = s1; red[4 + wv] = s2; }
    __syncthreads();
    if (tid == 0) {
        partials[b * 2 + 0] = red[0] + red[1] + red[2] + red[3];
        partials[b * 2 + 1] = red[4] + red[5] + red[6] + red[7];
    }
}

// ---------------- K1: reduce partials -> mean/rstd per n (deterministic) ----------------
__global__ __launch_bounds__(256) void stats_kernel(
    const float* __restrict__ partials, float* __restrict__ stats)
{
    const int tid = threadIdx.x;
    float a0 = 0, b0 = 0, a1 = 0, b1 = 0;
#pragma unroll
    for (int it = 0; it < 6; ++it) {
        int i = tid + it * 256;                       // conv block id
        float p1 = partials[i * 2 + 0], p2 = partials[i * 2 + 1];
        if (((i & 7) >> 2) == 0) { a0 += p1; b0 += p2; }   // xcd<4 -> n=0
        else                     { a1 += p1; b1 += p2; }
    }
#pragma unroll
    for (int off = 32; off; off >>= 1) {
        a0 += __shfl_down(a0, off, 64); b0 += __shfl_down(b0, off, 64);
        a1 += __shfl_down(a1, off, 64); b1 += __shfl_down(b1, off, 64);
    }
    __shared__ float red[4][4];
    const int lane = tid & 63, wv = tid >> 6;
    if (lane == 0) { red[wv][0] = a0; red[wv][1] = b0; red[wv][2] = a1; red[wv][3] = b1; }
    __syncthreads();
    if (tid == 0) {
        float A0 = red[0][0] + red[1][0] + red[2][0] + red[3][0];
        float B0 = red[0][1] + red[1][1] + red[2][1] + red[3][1];
        float A1 = red[0][2] + red[1][2] + red[2][2] + red[3][2];
        float B1 = red[0][3] + red[1][3] + red[2][3] + red[3][3];
        float m0 = A0 * (1.0f / (float)CHW_);
        float v0 = B0 * (1.0f / (float)CHW_) - m0 * m0;
        float m1 = A1 * (1.0f / (float)CHW_);
        float v1 = B1 * (1.0f / (float)CHW_) - m1 * m1;
        stats[0] = m0; stats[1] = rsqrtf(v0 + 1e-5f);
        stats[2] = m1; stats[3] = rsqrtf(v1 + 1e-5f);
    }
}

// ---------------- K2: norm+gelu -> MFMA om matmul -> softmax -> table -> sampling ----------------
__global__ __launch_bounds__(256, 5) void main_kernel(
    const __hip_bfloat16* __restrict__ xn, const float* __restrict__ unc,
    const __hip_bfloat16* __restrict__ ctx, const float* __restrict__ stats,
    const float* __restrict__ gn_w, const float* __restrict__ gn_b,
    const __hip_bfloat16* __restrict__ omwb, const float* __restrict__ om_b,
    float* __restrict__ out)
{
    // overlay plan (time-disjoint):
    //   [0,8448)       featb  short[16][264]    (Phase B->C)
    //   [0,4608)       tidx   uint2[576]        (D2->E)
    //   [4608,13824)   twt    float4[576]       (D2->E)
    //   [13824,21120)  oms    f32[16][114]      (C->D2)
    //   [13824,31232)  tbuf   f32[256][17]      (E->F)
    __shared__ __align__(16) char smem[31232];
    short* featb  = (short*)smem;
    uint2* tidx   = (uint2*)smem;
    float4* twt   = (float4*)(smem + 4608);
    float* oms    = (float*)(smem + 13824);
    float* tbuf   = (float*)(smem + 13824);

    const int tid = threadIdx.x;
    const int b = blockIdx.x;
    const int xcd = b & 7, bidx = b >> 3;
    const int tile = xcd * (NBLK / 8) + bidx;   // xcd owns contiguous rows -> L2 halo reuse
    const int n = tile / (H_ * NBW);
    const int rem = tile % (H_ * NBW);
    const int h = rem / NBW;
    const int w0 = (rem % NBW) * TILE;

    // ---- Phase B: ctx load + groupnorm + exact GELU -> feat bf16 (thread = channel) ----
    {
        const int c = tid;
        const float mean = stats[n * 2 + 0];
        const float rstd = stats[n * 2 + 1];
        const float gw = gn_w[c], gb = gn_b[c];
        const __hip_bfloat16* cb = ctx + ((size_t)(n * H_ + h) * W_ + w0) * C_ + c;
#pragma unroll
        for (int j = 0; j < TILE; ++j) {
            float v = __bfloat162float(cb[j * C_]);
            float f = (v - mean) * rstd * gw + gb;
            f = 0.5f * f * (1.0f + erff(f * 0.70710678118654752f));
            featb[j * FEATB_ST + c] = f2bf(f);
        }
    }
    __syncthreads();

    // ---- Phase C: om = feat @ om_w.T + om_b via MFMA 16x16x32 bf16 ----
    {
        const int wv = tid >> 6, lane = tid & 63;
        const int mrow = lane & 15, quad = lane >> 4;
        const short* fb  = featb + mrow * FEATB_ST;
        const short* wb0 = (const short*)omwb + (wv * 16 + mrow) * 256;
        const short* wb1 = (const short*)omwb + ((wv + 4) * 16 + mrow) * 256;
        f32x4 acc0 = {0.f, 0.f, 0.f, 0.f}, acc1 = {0.f, 0.f, 0.f, 0.f};
#pragma unroll
        for (int ks = 0; ks < 8; ++ks) {
            const int k = ks * 32 + quad * 8;
            bf16x8 a  = *(const bf16x8*)(fb + k);
            bf16x8 b0 = *(const bf16x8*)(wb0 + k);
            acc0 = __builtin_amdgcn_mfma_f32_16x16x32_bf16(a, b0, acc0, 0, 0, 0);
            if (wv < 3) {
                bf16x8 b1 = *(const bf16x8*)(wb1 + k);
                acc1 = __builtin_amdgcn_mfma_f32_16x16x32_bf16(a, b1, acc1, 0, 0, 0);
            }
        }
        const int j0 = wv * 16 + mrow;
        const float ob0 = om_b[j0];
#pragma unroll
        for (int rg = 0; rg < 4; ++rg)
            oms[(quad * 4 + rg) * OMS_ST + j0] = acc0[rg] + ob0;
        if (wv < 3) {
            const int j1 = (wv + 4) * 16 + mrow;
            if (j1 < OMC) {
                const float ob1 = om_b[j1];
#pragma unroll
                for (int rg = 0; rg < 4; ++rg)
                    oms[(quad * 4 + rg) * OMS_ST + j1] = acc1[rg] + ob1;
            }
        }
    }
    __syncthreads();

    // ---- Phase D1: softmax over P per (pixel, group) * uncertainty ----
    if (tid < TILE * G_) {
        int pix = tid >> 2, g = tid & 3;
        float* m = &oms[pix * OMS_ST + G_ * P_ * 2 + g * P_];
        float mx = m[0];
#pragma unroll
        for (int p = 1; p < P_; ++p) mx = fmaxf(mx, m[p]);
        float e[P_], s = 0.0f;
#pragma unroll
        for (int p = 0; p < P_; ++p) { e[p] = expf(m[p] - mx); s += e[p]; }
        float u = unc[(n * H_ + h) * W_ + w0 + pix];
        float inv = u / s;
#pragma unroll
        for (int p = 0; p < P_; ++p) m[p] = e[p] * inv;
    }
    __syncthreads();

    // ---- Phase D2: build tap table (SoA: packed u16 pixel indices + f32 weights) ----
    for (int e = tid; e < TILE * G_ * P_; e += 256) {   // 576 entries
        int pix = e / (G_ * P_);
        int rr = e - pix * (G_ * P_);
        int g = rr / P_, p = rr - g * P_;
        const float* po = &oms[pix * OMS_ST];
        float ox = po[(g * P_ + p) * 2 + 0];
        float oy = po[(g * P_ + p) * 2 + 1];
        float mk = po[G_ * P_ * 2 + g * P_ + p];
        float sx = (float)(w0 + pix + p / 3) + ox;
        float sy = (float)(h + p % 3) + oy;
        float x0f = floorf(sx), y0f = floorf(sy);
        float wx = sx - x0f, wy = sy - y0f;
        int x0 = (int)x0f - 1, y0 = (int)y0f - 1;       // top-left tap, unpadded
        float fy0 = (y0 >= 0 && y0 < H_) ? 1.0f : 0.0f;
        float fy1 = (y0 + 1 >= 0 && y0 + 1 < H_) ? 1.0f : 0.0f;
        float fx0 = (x0 >= 0 && x0 < W_) ? 1.0f : 0.0f;
        float fx1 = (x0 + 1 >= 0 && x0 + 1 < W_) ? 1.0f : 0.0f;
        int y0c = min(max(y0, 0), H_ - 1), y1c = min(max(y0 + 1, 0), H_ - 1);
        int x0c = min(max(x0, 0), W_ - 1), x1c = min(max(x0 + 1, 0), W_ - 1);
        unsigned i00 = (unsigned)(y0c * W_ + x0c), i01 = (unsigned)(y0c * W_ + x1c);
        unsigned i10 = (unsigned)(y1c * W_ + x0c), i11 = (unsigned)(y1c * W_ + x1c);
        tidx[e] = make_uint2(i00 | (i01 << 16), i10 | (i11 << 16));
        twt[e] = make_float4((1.0f - wy) * (1.0f - wx) * mk * fy0 * fx0,
                             (1.0f - wy) * wx * mk * fy0 * fx1,
                             wy * (1.0f - wx) * mk * fy1 * fx0,
                             wy * wx * mk * fy1 * fx1);
    }
    __syncthreads();

    // ---- Phase E: sampling; wave=group, lane=channel; coalesced NHWC taps ----
    {
        const int g = tid >> 6;
        const int lane = tid & 63;
        const __hip_bfloat16* xg = xn + (size_t)n * HW_ * C_ + g * GC_ + lane;
#pragma unroll 1
        for (int pix = 0; pix < TILE; ++pix) {
            const int te = pix * (G_ * P_) + g * P_;
            float acc = 0.0f;
#pragma unroll
            for (int p = 0; p < P_; ++p) {
                uint2 bi = tidx[te + p];
                float4 wt = twt[te + p];
                acc += wt.x * __bfloat162float(xg[(bi.x & 0xffffu) << 8])
                     + wt.y * __bfloat162float(xg[(bi.x >> 16) << 8])
                     + wt.z * __bfloat162float(xg[(bi.y & 0xffffu) << 8])
                     + wt.w * __bfloat162float(xg[(bi.y >> 16) << 8]);
            }
            tbuf[(g * GC_ + lane) * TBUF_ST + pix] = acc;
        }
    }
    __syncthreads();

    // ---- Phase F: full-line coalesced stores ----
    {
        const int px = tid & 15, c0 = tid >> 4;
        float* op = out + (size_t)n * CHW_ + (size_t)h * W_ + w0 + px;
#pragma unroll
        for (int k = 0; k < 16; ++k) {
            int c = c0 * 16 + k;
            op[(size_t)c * HW_] = tbuf[c * TBUF_ST + px];
        }
    }
}

extern "C" void kernel_launch(void* const* d_in, const int* in_sizes, int n_in,
                              void* d_out, int out_size, void* d_ws, size_t ws_size,
                              hipStream_t stream)
{
    const float* x    = (const float*)d_in[0];
    const float* unc  = (const float*)d_in[1];
    const float* dw_w = (const float*)d_in[2];
    const float* dw_b = (const float*)d_in[3];
    const float* gn_w = (const float*)d_in[4];
    const float* gn_b = (const float*)d_in[5];
    const float* om_w = (const float*)d_in[6];
    const float* om_b = (const float*)d_in[7];
    float* out = (float*)d_out;

    float* partials      = (float*)d_ws;
    float* stats         = (float*)((char*)d_ws + 12288);
    __hip_bfloat16* omwb = (__hip_bfloat16*)((char*)d_ws + 16384);
    __hip_bfloat16* xn   = (__hip_bfloat16*)((char*)d_ws + 81920);
    __hip_bfloat16* ctx  = xn + (size_t)N_ * HW_ * C_;

    prep_kernel<<<NCONV + NOMW, 256, 0, stream>>>(x, dw_w, dw_b, om_w, xn, ctx, omwb, partials);
    stats_kernel<<<1, 256, 0, stream>>>(partials, stats);
    main_kernel<<<NBLK, 256, 0, stream>>>(xn, unc, ctx, stats,
                                          gn_w, gn_b, omwb, om_b, out);
}

// Round 11
// 138.318 us; speedup vs baseline: 11.8139x; 1.0107x over previous
//
#include <hip/hip_runtime.h>
#include <hip/hip_bf16.h>
#include <hip/hip_fp16.h>
#include <math.h>

#define C_   256
#define G_   4
#define P_   9
#define GC_  64
#define H_   96
#define W_   96
#define N_   2
#define HW_  (H_*W_)          // 9216
#define CHW_ (C_*H_*W_)       // 2359296
#define OMC  108              // G*P*3
#define OMR  112              // padded rows of om_w bf16 copy
#define TILE 16               // pixels along w per block (main)
#define NBW  (W_/TILE)        // 6
#define NBLK (N_*H_*NBW)      // 1152 main tiles
#define NCONV 768             // prep conv blocks: N*(H/4)*(C/16)
#define NOMW  16              // prep tail blocks converting om_w
#define CH_ST 628             // shorts per channel in prep LDS (6 rows x 104, +pad; 8B-aligned, 2-way banks = free)
#define ROW_ST 104            // shorts per staged row: [0,1]=pad, [4+w] w=0..95, [2,3]=left-halo zeros, [100,101]=right-halo zeros
#define FEATB_ST 264          // shorts per pixel row in main
#define OMS_ST 114
#define TBUF_ST 17

typedef __attribute__((ext_vector_type(8))) short bf16x8;
typedef __attribute__((ext_vector_type(4))) float f32x4;

__device__ __forceinline__ short f2bf(float f) {
    __hip_bfloat16 h = __float2bfloat16(f);
    return *reinterpret_cast<short*>(&h);
}
__device__ __forceinline__ unsigned short f2bfu(float f) {
    return (unsigned short)f2bf(f);
}
__device__ __forceinline__ float bflo(unsigned u) {
    union { unsigned q; float f; } v; v.q = u << 16; return v.f;
}
__device__ __forceinline__ float bfhi(unsigned u) {
    union { unsigned q; float f; } v; v.q = u & 0xffff0000u; return v.f;
}

// ws layout (bytes):
//   [0)      partials: NCONV*2 floats (6144 B), deterministic per-block sums
//   [12288)  stats: 4 floats {mean0, rstd0, mean1, rstd1}
//   [16384)  omwb: 112*256 bf16 (57344 B)
//   [81920)  xn  bf16 NHWC (9.44 MB)
//   [+)      ctx bf16 NHWC (9.44 MB)
// NOTE: no atomics anywhere — replay re-validation requires bit-identical
// output across calls. All LDS regions read are initialized every call.

// ---------------- K0: prep — conv blocks (16ch x 4 rows, bf16-staged) + omwb tail ----------------
__global__ __launch_bounds__(256) void prep_kernel(
    const float* __restrict__ x, const float* __restrict__ dw_w,
    const float* __restrict__ dw_b, const float* __restrict__ om_w,
    __hip_bfloat16* __restrict__ xn, __hip_bfloat16* __restrict__ ctx,
    __hip_bfloat16* __restrict__ omwb, float* __restrict__ partials)
{
    const int b = blockIdx.x;
    const int tid = threadIdx.x;

    if (b >= NCONV) {
        // ---- om_w f32[108][256] -> omwb bf16[112][256] (rows 108..111 zero) ----
        const int bb = b - NCONV;                    // 0..15
        const float4* src = (const float4*)om_w;     // 6912 float4 valid
        ushort4* dst = (ushort4*)omwb;               // 7168 ushort4 total
#pragma unroll
        for (int it = 0; it < 2; ++it) {
            int i = tid + it * 256;
            if (i < 448) {
                int fi = bb * 448 + i;
                float4 v = (fi < 6912) ? src[fi] : make_float4(0.f, 0.f, 0.f, 0.f);
                ushort4 u;
                u.x = f2bfu(v.x); u.y = f2bfu(v.y);
                u.z = f2bfu(v.z); u.w = f2bfu(v.w);
                dst[fi] = u;
            }
        }
        return;
    }

    // ---- conv block: 16 channels x 4 output rows ----
    __shared__ short xs[16 * CH_ST];   // 20096 B, bf16-staged x (R5-validated numerics)
    __shared__ float red[8];
    const int xcd = b & 7, q = b >> 3;           // q in [0,96)
    const int nh4 = xcd * 6 + (q >> 4);          // row-quad [0,48), xcd owns 24 contiguous rows
    const int ct = q & 15;                       // channel group [0,16)
    const int n = nh4 / 24, h0 = (nh4 % 24) * 4;
    const int c0 = ct * 16;

    // zero halo slots: shorts [2,3] (cols -2,-1) and [100,101] (cols 96,97) per (c,row)
    if (tid < 96) {
        int c = tid / 6, r = tid % 6;
        unsigned* zp = (unsigned*)xs;
        zp[c * (CH_ST / 2) + r * (ROW_ST / 2) + 1]  = 0u;   // shorts 2,3
        zp[c * (CH_ST / 2) + r * (ROW_ST / 2) + 50] = 0u;   // shorts 100,101
    }
    // stage x[c0..c0+16, h0-1..h0+4, 0..96) f32 -> bf16 LDS via coalesced float4
    {
        ushort4* xsv = (ushort4*)xs;
#pragma unroll
        for (int it = 0; it < 9; ++it) {
            int idx = tid + it * 256;            // 0..2303
            int row = idx / 24;                  // c*6 + r
            int col4 = idx % 24;
            int c = row / 6, r = row % 6;
            int gy = h0 - 1 + r;
            ushort4 u = make_ushort4(0, 0, 0, 0);
            if (gy >= 0 && gy < H_) {
                float4 v = *(const float4*)&x[(size_t)(n * C_ + c0 + c) * HW_ + gy * W_ + col4 * 4];
                u.x = f2bfu(v.x); u.y = f2bfu(v.y);
                u.z = f2bfu(v.z); u.w = f2bfu(v.w);
            }
            xsv[c * (CH_ST / 4) + r * (ROW_ST / 4) + 1 + col4] = u;   // shorts 4+4*col4
        }
    }
    __syncthreads();

    // thread = (c = tid&15, slot = tid>>4): slot = jr*8 + ws; jr: out-row pair, ws: 12-px w-slot
    const int c = tid & 15;
    const int slot = tid >> 4;
    const int jr = slot >> 3;                    // 0..1 -> out rows {2jr, 2jr+1}
    const int ws = slot & 7;
    const int W0 = ws * 12;
    float wgt[9];
#pragma unroll
    for (int kq = 0; kq < 9; ++kq) wgt[kq] = dw_w[(c0 + c) * 9 + kq];
    const float bias = dw_b[c0 + c];

    float s1 = 0.0f, s2 = 0.0f;
#pragma unroll
    for (int jj = 0; jj < 2; ++jj) {
        const int j = jr * 2 + jj;               // out row offset 0..3
        float acc[12];
#pragma unroll
        for (int px = 0; px < 12; ++px) acc[px] = bias;
        float xnv[12];
#pragma unroll
        for (int r3 = 0; r3 < 3; ++r3) {
            // staged row j+r3; window shorts [W0+2 .. W0+17] = cols [W0-2 .. W0+13]
            const unsigned* rp = (const unsigned*)xs
                               + c * (CH_ST / 2) + (j + r3) * (ROW_ST / 2) + 6 * ws + 1;
            float vals[16];
#pragma unroll
            for (int i = 0; i < 8; ++i) {
                unsigned u = rp[i];
                vals[2 * i]     = bflo(u);
                vals[2 * i + 1] = bfhi(u);
            }
            const float w0v = wgt[r3 * 3 + 0], w1v = wgt[r3 * 3 + 1], w2v = wgt[r3 * 3 + 2];
#pragma unroll
            for (int px = 0; px < 12; ++px)
                acc[px] += w0v * vals[px + 1] + w1v * vals[px + 2] + w2v * vals[px + 3];
            if (r3 == 1) {
#pragma unroll
                for (int px = 0; px < 12; ++px) xnv[px] = vals[px + 2];   // col W0+px
            }
        }
        const int gh = h0 + j;
        __hip_bfloat16* cb = ctx + ((size_t)(n * H_ + gh) * W_ + W0) * C_ + c0 + c;
        __hip_bfloat16* xb = xn  + ((size_t)(n * H_ + gh) * W_ + W0) * C_ + c0 + c;
#pragma unroll
        for (int px = 0; px < 12; ++px) {
            float v = acc[px];
            s1 += v; s2 += v * v;
            cb[px * C_] = __float2bfloat16(v);
            xb[px * C_] = __float2bfloat16(xnv[px]);   // identity re-round of staged bf16
        }
    }
#pragma unroll
    for (int off = 32; off; off >>= 1) {
        s1 += __shfl_down(s1, off, 64);
        s2 += __shfl_down(s2, off, 64);
    }
    const int lane = tid & 63, wv = tid >> 6;
    if (lane == 0) { red[wv] = s1; red[4 + wv] = s2; }
    __syncthreads();
    if (tid == 0) {
        partials[b * 2 + 0] = red[0] + red[1] + red[2] + red[3];
        partials[b * 2 + 1] = red[4] + red[5] + red[6] + red[7];
    }
}

// ---------------- K1: reduce partials -> mean/rstd per n (deterministic) ----------------
__global__ __launch_bounds__(256) void stats_kernel(
    const float* __restrict__ partials, float* __restrict__ stats)
{
    const int tid = threadIdx.x;
    float a0 = 0, b0 = 0, a1 = 0, b1 = 0;
#pragma unroll
    for (int it = 0; it < 3; ++it) {
        int i = tid + it * 256;                       // conv block id [0,768)
        float p1 = partials[i * 2 + 0], p2 = partials[i * 2 + 1];
        if (((i & 7) >> 2) == 0) { a0 += p1; b0 += p2; }   // xcd<4 -> n=0
        else                     { a1 += p1; b1 += p2; }
    }
#pragma unroll
    for (int off = 32; off; off >>= 1) {
        a0 += __shfl_down(a0, off, 64); b0 += __shfl_down(b0, off, 64);
        a1 += __shfl_down(a1, off, 64); b1 += __shfl_down(b1, off, 64);
    }
    __shared__ float red[4][4];
    const int lane = tid & 63, wv = tid >> 6;
    if (lane == 0) { red[wv][0] = a0; red[wv][1] = b0; red[wv][2] = a1; red[wv][3] = b1; }
    __syncthreads();
    if (tid == 0) {
        float A0 = red[0][0] + red[1][0] + red[2][0] + red[3][0];
        float B0 = red[0][1] + red[1][1] + red[2][1] + red[3][1];
        float A1 = red[0][2] + red[1][2] + red[2][2] + red[3][2];
        float B1 = red[0][3] + red[1][3] + red[2][3] + red[3][3];
        float m0 = A0 * (1.0f / (float)CHW_);
        float v0 = B0 * (1.0f / (float)CHW_) - m0 * m0;
        float m1 = A1 * (1.0f / (float)CHW_);
        float v1 = B1 * (1.0f / (float)CHW_) - m1 * m1;
        stats[0] = m0; stats[1] = rsqrtf(v0 + 1e-5f);
        stats[2] = m1; stats[3] = rsqrtf(v1 + 1e-5f);
    }
}

// ---------------- K2: norm+gelu -> MFMA om matmul -> softmax -> table -> sampling ----------------
// (byte-identical to the R10-validated main_kernel)
__global__ __launch_bounds__(256, 5) void main_kernel(
    const __hip_bfloat16* __restrict__ xn, const float* __restrict__ unc,
    const __hip_bfloat16* __restrict__ ctx, const float* __restrict__ stats,
    const float* __restrict__ gn_w, const float* __restrict__ gn_b,
    const __hip_bfloat16* __restrict__ omwb, const float* __restrict__ om_b,
    float* __restrict__ out)
{
    // overlay plan (time-disjoint):
    //   [0,8448)       featb  short[16][264]    (Phase B->C)
    //   [0,4608)       tidx   uint2[576]        (D2->E)
    //   [4608,13824)   twt    float4[576]       (D2->E)
    //   [13824,21120)  oms    f32[16][114]      (C->D2)
    //   [13824,31232)  tbuf   f32[256][17]      (E->F)
    __shared__ __align__(16) char smem[31232];
    short* featb  = (short*)smem;
    uint2* tidx   = (uint2*)smem;
    float4* twt   = (float4*)(smem + 4608);
    float* oms    = (float*)(smem + 13824);
    float* tbuf   = (float*)(smem + 13824);

    const int tid = threadIdx.x;
    const int b = blockIdx.x;
    const int xcd = b & 7, bidx = b >> 3;
    const int tile = xcd * (NBLK / 8) + bidx;   // xcd owns contiguous rows -> L2 halo reuse
    const int n = tile / (H_ * NBW);
    const int rem = tile % (H_ * NBW);
    const int h = rem / NBW;
    const int w0 = (rem % NBW) * TILE;

    // ---- Phase B: ctx load + groupnorm + exact GELU -> feat bf16 (thread = channel) ----
    {
        const int c = tid;
        const float mean = stats[n * 2 + 0];
        const float rstd = stats[n * 2 + 1];
        const float gw = gn_w[c], gb = gn_b[c];
        const __hip_bfloat16* cb = ctx + ((size_t)(n * H_ + h) * W_ + w0) * C_ + c;
#pragma unroll
        for (int j = 0; j < TILE; ++j) {
            float v = __bfloat162float(cb[j * C_]);
            float f = (v - mean) * rstd * gw + gb;
            f = 0.5f * f * (1.0f + erff(f * 0.70710678118654752f));
            featb[j * FEATB_ST + c] = f2bf(f);
        }
    }
    __syncthreads();

    // ---- Phase C: om = feat @ om_w.T + om_b via MFMA 16x16x32 bf16 ----
    {
        const int wv = tid >> 6, lane = tid & 63;
        const int mrow = lane & 15, quad = lane >> 4;
        const short* fb  = featb + mrow * FEATB_ST;
        const short* wb0 = (const short*)omwb + (wv * 16 + mrow) * 256;
        const short* wb1 = (const short*)omwb + ((wv + 4) * 16 + mrow) * 256;
        f32x4 acc0 = {0.f, 0.f, 0.f, 0.f}, acc1 = {0.f, 0.f, 0.f, 0.f};
#pragma unroll
        for (int ks = 0; ks < 8; ++ks) {
            const int k = ks * 32 + quad * 8;
            bf16x8 a  = *(const bf16x8*)(fb + k);
            bf16x8 b0 = *(const bf16x8*)(wb0 + k);
            acc0 = __builtin_amdgcn_mfma_f32_16x16x32_bf16(a, b0, acc0, 0, 0, 0);
            if (wv < 3) {
                bf16x8 b1 = *(const bf16x8*)(wb1 + k);
                acc1 = __builtin_amdgcn_mfma_f32_16x16x32_bf16(a, b1, acc1, 0, 0, 0);
            }
        }
        const int j0 = wv * 16 + mrow;
        const float ob0 = om_b[j0];
#pragma unroll
        for (int rg = 0; rg < 4; ++rg)
            oms[(quad * 4 + rg) * OMS_ST + j0] = acc0[rg] + ob0;
        if (wv < 3) {
            const int j1 = (wv + 4) * 16 + mrow;
            if (j1 < OMC) {
                const float ob1 = om_b[j1];
#pragma unroll
                for (int rg = 0; rg < 4; ++rg)
                    oms[(quad * 4 + rg) * OMS_ST + j1] = acc1[rg] + ob1;
            }
        }
    }
    __syncthreads();

    // ---- Phase D1: softmax over P per (pixel, group) * uncertainty ----
    if (tid < TILE * G_) {
        int pix = tid >> 2, g = tid & 3;
        float* m = &oms[pix * OMS_ST + G_ * P_ * 2 + g * P_];
        float mx = m[0];
#pragma unroll
        for (int p = 1; p < P_; ++p) mx = fmaxf(mx, m[p]);
        float e[P_], s = 0.0f;
#pragma unroll
        for (int p = 0; p < P_; ++p) { e[p] = expf(m[p] - mx); s += e[p]; }
        float u = unc[(n * H_ + h) * W_ + w0 + pix];
        float inv = u / s;
#pragma unroll
        for (int p = 0; p < P_; ++p) m[p] = e[p] * inv;
    }
    __syncthreads();

    // ---- Phase D2: build tap table (SoA: packed u16 pixel indices + f32 weights) ----
    for (int e = tid; e < TILE * G_ * P_; e += 256) {   // 576 entries
        int pix = e / (G_ * P_);
        int rr = e - pix * (G_ * P_);
        int g = rr / P_, p = rr - g * P_;
        const float* po = &oms[pix * OMS_ST];
        float ox = po[(g * P_ + p) * 2 + 0];
        float oy = po[(g * P_ + p) * 2 + 1];
        float mk = po[G_ * P_ * 2 + g * P_ + p];
        float sx = (float)(w0 + pix + p / 3) + ox;
        float sy = (float)(h + p % 3) + oy;
        float x0f = floorf(sx), y0f = floorf(sy);
        float wx = sx - x0f, wy = sy - y0f;
        int x0 = (int)x0f - 1, y0 = (int)y0f - 1;       // top-left tap, unpadded
        float fy0 = (y0 >= 0 && y0 < H_) ? 1.0f : 0.0f;
        float fy1 = (y0 + 1 >= 0 && y0 + 1 < H_) ? 1.0f : 0.0f;
        float fx0 = (x0 >= 0 && x0 < W_) ? 1.0f : 0.0f;
        float fx1 = (x0 + 1 >= 0 && x0 + 1 < W_) ? 1.0f : 0.0f;
        int y0c = min(max(y0, 0), H_ - 1), y1c = min(max(y0 + 1, 0), H_ - 1);
        int x0c = min(max(x0, 0), W_ - 1), x1c = min(max(x0 + 1, 0), W_ - 1);
        unsigned i00 = (unsigned)(y0c * W_ + x0c), i01 = (unsigned)(y0c * W_ + x1c);
        unsigned i10 = (unsigned)(y1c * W_ + x0c), i11 = (unsigned)(y1c * W_ + x1c);
        tidx[e] = make_uint2(i00 | (i01 << 16), i10 | (i11 << 16));
        twt[e] = make_float4((1.0f - wy) * (1.0f - wx) * mk * fy0 * fx0,
                             (1.0f - wy) * wx * mk * fy0 * fx1,
                             wy * (1.0f - wx) * mk * fy1 * fx0,
                             wy * wx * mk * fy1 * fx1);
    }
    __syncthreads();

    // ---- Phase E: sampling; wave=group, lane=channel; coalesced NHWC taps ----
    {
        const int g = tid >> 6;
        const int lane = tid & 63;
        const __hip_bfloat16* xg = xn + (size_t)n * HW_ * C_ + g * GC_ + lane;
#pragma unroll 1
        for (int pix = 0; pix < TILE; ++pix) {
            const int te = pix * (G_ * P_) + g * P_;
            float acc = 0.0f;
#pragma unroll
            for (int p = 0; p < P_; ++p) {
                uint2 bi = tidx[te + p];
                float4 wt = twt[te + p];
                acc += wt.x * __bfloat162float(xg[(bi.x & 0xffffu) << 8])
                     + wt.y * __bfloat162float(xg[(bi.x >> 16) << 8])
                     + wt.z * __bfloat162float(xg[(bi.y & 0xffffu) << 8])
                     + wt.w * __bfloat162float(xg[(bi.y >> 16) << 8]);
            }
            tbuf[(g * GC_ + lane) * TBUF_ST + pix] = acc;
        }
    }
    __syncthreads();

    // ---- Phase F: full-line coalesced stores ----
    {
        const int px = tid & 15, c0 = tid >> 4;
        float* op = out + (size_t)n * CHW_ + (size_t)h * W_ + w0 + px;
#pragma unroll
        for (int k = 0; k < 16; ++k) {
            int c = c0 * 16 + k;
            op[(size_t)c * HW_] = tbuf[c * TBUF_ST + px];
        }
    }
}

extern "C" void kernel_launch(void* const* d_in, const int* in_sizes, int n_in,
                              void* d_out, int out_size, void* d_ws, size_t ws_size,
                              hipStream_t stream)
{
    const float* x    = (const float*)d_in[0];
    const float* unc  = (const float*)d_in[1];
    const float* dw_w = (const float*)d_in[2];
    const float* dw_b = (const float*)d_in[3];
    const float* gn_w = (const float*)d_in[4];
    const float* gn_b = (const float*)d_in[5];
    const float* om_w = (const float*)d_in[6];
    const float* om_b = (const float*)d_in[7];
    float* out = (float*)d_out;

    float* partials      = (float*)d_ws;
    float* stats         = (float*)((char*)d_ws + 12288);
    __hip_bfloat16* omwb = (__hip_bfloat16*)((char*)d_ws + 16384);
    __hip_bfloat16* xn   = (__hip_bfloat16*)((char*)d_ws + 81920);
    __hip_bfloat16* ctx  = xn + (size_t)N_ * HW_ * C_;

    prep_kernel<<<NCONV + NOMW, 256, 0, stream>>>(x, dw_w, dw_b, om_w, xn, ctx, omwb, partials);
    stats_kernel<<<1, 256, 0, stream>>>(partials, stats);
    main_kernel<<<NBLK, 256, 0, stream>>>(xn, unc, ctx, stats,
                                          gn_w, gn_b, omwb, om_b, out);
}